// Round 1
// 609.928 us; speedup vs baseline: 1.0007x; 1.0007x over previous
//
#include <hip/hip_runtime.h>
#include <hip/hip_bf16.h>
#include <cstdint>
#include <cstddef>

// ---------- types ----------
typedef __bf16 bf16x8 __attribute__((ext_vector_type(8)));
typedef float  f32x4  __attribute__((ext_vector_type(4)));

__device__ __forceinline__ unsigned short f2bf(float f) {
  union { float f; unsigned u; } v; v.f = f;
  unsigned u = v.u;
  u += 0x7FFFu + ((u >> 16) & 1u);   // RNE
  return (unsigned short)(u >> 16);
}

// native cast path: compiler emits v_cvt_pk_bf16_f32 (RNE, same rounding as f2bf)
__device__ __forceinline__ unsigned short f2bf_cvt(float f) {
  __bf16 h = (__bf16)f;
  return __builtin_bit_cast(unsigned short, h);
}

struct alignas(16) US8 { unsigned short u[8]; };

__device__ __forceinline__ void g2lds16(const void* g, void* l) {
  __builtin_amdgcn_global_load_lds(
      (const __attribute__((address_space(1))) unsigned int*)g,
      (__attribute__((address_space(3))) unsigned int*)l, 16, 0, 0);
}

// sizes
#define BB 2
#define SS 1024
#define HID 1024
#define NHH 16
#define HDD 64
#define TT 4096
#define CCH 3072

// ---------- LayerNorm (complex) -> Aln bf16 [2048][2048] = [nr | ni] ----------
__global__ __launch_bounds__(256) void ln_kernel(
    const float* __restrict__ hre, const float* __restrict__ him,
    const float* __restrict__ gamma, const float* __restrict__ bre,
    const float* __restrict__ bim, unsigned short* __restrict__ Aln)
{
  int m = blockIdx.x;
  int tid = threadIdx.x;
  const float4 vr = ((const float4*)(hre + (size_t)m * HID))[tid];
  const float4 vi = ((const float4*)(him + (size_t)m * HID))[tid];
  float sr = vr.x + vr.y + vr.z + vr.w;
  float si = vi.x + vi.y + vi.z + vi.w;
  float sq = vr.x*vr.x + vr.y*vr.y + vr.z*vr.z + vr.w*vr.w
           + vi.x*vi.x + vi.y*vi.y + vi.z*vi.z + vi.w*vi.w;
  __shared__ float red[3][4];
  int lane = tid & 63, w = tid >> 6;
  for (int off = 32; off; off >>= 1) {
    sr += __shfl_down(sr, off, 64);
    si += __shfl_down(si, off, 64);
    sq += __shfl_down(sq, off, 64);
  }
  if (lane == 0) { red[0][w] = sr; red[1][w] = si; red[2][w] = sq; }
  __syncthreads();
  sr = red[0][0] + red[0][1] + red[0][2] + red[0][3];
  si = red[1][0] + red[1][1] + red[1][2] + red[1][3];
  sq = red[2][0] + red[2][1] + red[2][2] + red[2][3];
  float mur = sr * (1.f/1024.f), mui = si * (1.f/1024.f);
  float var = sq * (1.f/1024.f) - mur*mur - mui*mui;
  float inv = rsqrtf(var + 1e-5f);
  int k = tid * 4;
  float4 g  = ((const float4*)gamma)[tid];
  float4 br = ((const float4*)bre)[tid];
  float4 bi = ((const float4*)bim)[tid];
  ushort4 nr, ni;
  nr.x = f2bf((vr.x - mur) * inv * g.x + br.x);
  nr.y = f2bf((vr.y - mur) * inv * g.y + br.y);
  nr.z = f2bf((vr.z - mur) * inv * g.z + br.z);
  nr.w = f2bf((vr.w - mur) * inv * g.w + br.w);
  ni.x = f2bf((vi.x - mui) * inv * g.x + bi.x);
  ni.y = f2bf((vi.y - mui) * inv * g.y + bi.y);
  ni.z = f2bf((vi.z - mui) * inv * g.z + bi.z);
  ni.w = f2bf((vi.w - mui) * inv * g.w + bi.w);
  *(ushort4*)&Aln[(size_t)m * 2048 + k]        = nr;
  *(ushort4*)&Aln[(size_t)m * 2048 + 1024 + k] = ni;
}

// ---------- combined weights: Wc[p][n][k] bf16, p in {q,k,v,o}, 2048x2048 each ----------
__global__ __launch_bounds__(256) void wprep_kernel(
    const float* __restrict__ qWr, const float* __restrict__ qWi,
    const float* __restrict__ kWr, const float* __restrict__ kWi,
    const float* __restrict__ vWr, const float* __restrict__ vWi,
    const float* __restrict__ oWr, const float* __restrict__ oWi,
    unsigned short* __restrict__ Wc)
{
  int gid = blockIdx.x * 256 + threadIdx.x;
  int idx = gid * 8;                     // over 4*2048*2048
  int p   = idx >> 22;
  int rem = idx & 0x3FFFFF;
  int n   = rem >> 11;
  int k   = rem & 2047;
  const float* Wr; const float* Wi;
  switch (p) {
    case 0:  Wr = qWr; Wi = qWi; break;
    case 1:  Wr = kWr; Wi = kWi; break;
    case 2:  Wr = vWr; Wi = vWi; break;
    default: Wr = oWr; Wi = oWi; break;
  }
  const float* src; float sgn = 1.f;
  if (n < 1024) {
    if (k < 1024) src = Wr + (size_t)n * 1024 + k;
    else        { src = Wi + (size_t)n * 1024 + (k - 1024); sgn = -1.f; }
  } else {
    if (k < 1024) src = Wi + (size_t)(n - 1024) * 1024 + k;
    else          src = Wr + (size_t)(n - 1024) * 1024 + (k - 1024);
  }
  float4 a = ((const float4*)src)[0];
  float4 b = ((const float4*)src)[1];
  US8 o;
  o.u[0] = f2bf(a.x * sgn); o.u[1] = f2bf(a.y * sgn);
  o.u[2] = f2bf(a.z * sgn); o.u[3] = f2bf(a.w * sgn);
  o.u[4] = f2bf(b.x * sgn); o.u[5] = f2bf(b.y * sgn);
  o.u[6] = f2bf(b.z * sgn); o.u[7] = f2bf(b.w * sgn);
  *(US8*)&Wc[idx] = o;
}

__global__ __launch_bounds__(256) void bprep_kernel(
    const float* __restrict__ qbr, const float* __restrict__ qbi,
    const float* __restrict__ kbr, const float* __restrict__ kbi,
    const float* __restrict__ vbr, const float* __restrict__ vbi,
    const float* __restrict__ obr, const float* __restrict__ obi,
    float* __restrict__ bc)
{
  int idx = blockIdx.x * 256 + threadIdx.x;  // 8192
  int p = idx >> 11, n = idx & 2047;
  const float* br; const float* bi;
  switch (p) {
    case 0:  br = qbr; bi = qbi; break;
    case 1:  br = kbr; bi = kbi; break;
    case 2:  br = vbr; bi = vbi; break;
    default: br = obr; bi = obi; break;
  }
  bc[idx] = (n < 1024) ? br[n] : bi[n - 1024];
}

// ---------- GEMM: C[M x N] = A[M x K] * B[N x K]^T + bias[n], bf16 in, f32 out ----------
// staging via global_load_lds width=16 (m97 structure): LDS layout is linear in tid
// (byte offset = 16*tid), which is exactly the wave-uniform-base + lane*16 pattern
// the DMA requires.
__global__ __launch_bounds__(256) void gemm_bt_kernel(
    const unsigned short* __restrict__ A, const unsigned short* __restrict__ Bm,
    const float* __restrict__ bias, float* __restrict__ C, int Nstride, int K)
{
  __shared__ alignas(16) unsigned short As[128][32];
  __shared__ alignas(16) unsigned short Bs[128][32];
  int bm = blockIdx.y * 128;
  int bn = blockIdx.x * 128;
  int tid = threadIdx.x;
  int lane = tid & 63, w = tid >> 6;
  int wm = (w >> 1) * 64, wn = (w & 1) * 64;
  int l15 = lane & 15, q = lane >> 4;
  int lr = tid >> 2;            // 0..63
  int lc = (tid & 3) * 8;       // 0,8,16,24

  f32x4 acc[4][4] = {};

  for (int k0 = 0; k0 < K; k0 += 32) {
    // As[lr][lc] element offset = 8*tid ; As[lr+64][lc] = 8*tid + 2048 (both linear in tid)
    g2lds16(&A [(size_t)(bm + lr)      * K + k0 + lc], (unsigned short*)As + 8*tid);
    g2lds16(&A [(size_t)(bm + lr + 64) * K + k0 + lc], (unsigned short*)As + 2048 + 8*tid);
    g2lds16(&Bm[(size_t)(bn + lr)      * K + k0 + lc], (unsigned short*)Bs + 8*tid);
    g2lds16(&Bm[(size_t)(bn + lr + 64) * K + k0 + lc], (unsigned short*)Bs + 2048 + 8*tid);
    __syncthreads();            // compiler drains vmcnt before s_barrier
    bf16x8 af[4], bfr[4];
#pragma unroll
    for (int i = 0; i < 4; i++) af[i]  = *(const bf16x8*)&As[wm + i*16 + l15][q*8];
#pragma unroll
    for (int i = 0; i < 4; i++) bfr[i] = *(const bf16x8*)&Bs[wn + i*16 + l15][q*8];
#pragma unroll
    for (int i = 0; i < 4; i++)
#pragma unroll
      for (int j = 0; j < 4; j++)
        acc[i][j] = __builtin_amdgcn_mfma_f32_16x16x32_bf16(af[i], bfr[j], acc[i][j], 0, 0, 0);
    __syncthreads();
  }

#pragma unroll
  for (int i = 0; i < 4; i++)
#pragma unroll
    for (int j = 0; j < 4; j++) {
      int n = bn + wn + j*16 + l15;
      float bv = bias[n];
#pragma unroll
      for (int r = 0; r < 4; r++) {
        int m = bm + wm + i*16 + q*4 + r;
        C[(size_t)m * Nstride + n] = acc[i][j][r] + bv;
      }
    }
}

// ---------- o-proj GEMM with residual + split write to out_re/out_im ----------
__global__ __launch_bounds__(256) void gemm_oproj_kernel(
    const unsigned short* __restrict__ A, const unsigned short* __restrict__ Bm,
    const float* __restrict__ bias, const float* __restrict__ hre,
    const float* __restrict__ him, float* __restrict__ out)
{
  __shared__ alignas(16) unsigned short As[128][32];
  __shared__ alignas(16) unsigned short Bs[128][32];
  int bm = blockIdx.y * 128;
  int bn = blockIdx.x * 128;
  int tid = threadIdx.x;
  int lane = tid & 63, w = tid >> 6;
  int wm = (w >> 1) * 64, wn = (w & 1) * 64;
  int l15 = lane & 15, q = lane >> 4;
  int lr = tid >> 2;
  int lc = (tid & 3) * 8;
  const int K = 2048;

  f32x4 acc[4][4] = {};

  for (int k0 = 0; k0 < K; k0 += 32) {
    g2lds16(&A [(size_t)(bm + lr)      * K + k0 + lc], (unsigned short*)As + 8*tid);
    g2lds16(&A [(size_t)(bm + lr + 64) * K + k0 + lc], (unsigned short*)As + 2048 + 8*tid);
    g2lds16(&Bm[(size_t)(bn + lr)      * K + k0 + lc], (unsigned short*)Bs + 8*tid);
    g2lds16(&Bm[(size_t)(bn + lr + 64) * K + k0 + lc], (unsigned short*)Bs + 2048 + 8*tid);
    __syncthreads();
    bf16x8 af[4], bfr[4];
#pragma unroll
    for (int i = 0; i < 4; i++) af[i]  = *(const bf16x8*)&As[wm + i*16 + l15][q*8];
#pragma unroll
    for (int i = 0; i < 4; i++) bfr[i] = *(const bf16x8*)&Bs[wn + i*16 + l15][q*8];
#pragma unroll
    for (int i = 0; i < 4; i++)
#pragma unroll
      for (int j = 0; j < 4; j++)
        acc[i][j] = __builtin_amdgcn_mfma_f32_16x16x32_bf16(af[i], bfr[j], acc[i][j], 0, 0, 0);
    __syncthreads();
  }

#pragma unroll
  for (int i = 0; i < 4; i++)
#pragma unroll
    for (int j = 0; j < 4; j++) {
      int n = bn + wn + j*16 + l15;
      float bv = bias[n];
#pragma unroll
      for (int r = 0; r < 4; r++) {
        int m = bm + wm + i*16 + q*4 + r;
        float val = acc[i][j][r] + bv;
        if (n < 1024) out[(size_t)m * 1024 + n] = val + hre[(size_t)m * 1024 + n];
        else out[2097152 + (size_t)m * 1024 + (n - 1024)] = val + him[(size_t)m * 1024 + (n - 1024)];
      }
    }
}

// ---------- pack Q: Cqkv cols [0,2048) -> Qp[bh][s][128] bf16, scaled by 1/8 ----------
__global__ __launch_bounds__(256) void pack_q_kernel(
    const float* __restrict__ Cqkv, unsigned short* __restrict__ Qp)
{
  int gid = blockIdx.x * 256 + threadIdx.x;
  int idx = gid * 4;                 // over 2*16*1024*128 = 4,194,304
  int d2 = idx & 127;
  int s  = (idx >> 7) & 1023;
  int bh = idx >> 17;
  int b = bh >> 4, h = bh & 15;
  int d = d2 & 63;
  int col = (d2 < 64) ? (h*64 + d) : (1024 + h*64 + d);
  float4 v = *(const float4*)&Cqkv[((size_t)b * 1024 + s) * 6144 + col];
  ushort4 o;
  o.x = f2bf(v.x * 0.125f); o.y = f2bf(v.y * 0.125f);
  o.z = f2bf(v.z * 0.125f); o.w = f2bf(v.w * 0.125f);
  *(ushort4*)&Qp[idx] = o;
}

// ---------- pack K or V: cache + Cqkv -> packed bf16 [bh][t][128] (optional) + new_* f32 outputs ----------
__global__ __launch_bounds__(256) void pack_kv_kernel(
    const float* __restrict__ c_re, const float* __restrict__ c_im,
    const float* __restrict__ Cqkv, int colbase,
    unsigned short* __restrict__ Kp,
    float* __restrict__ out_re, float* __restrict__ out_im)
{
  int gid = blockIdx.x * 256 + threadIdx.x;
  int idx = gid * 4;                 // over 2*16*4096*128 = 16,777,216
  int d2 = idx & 127;
  int t  = (idx >> 7) & 4095;
  int bh = idx >> 19;
  int b = bh >> 4, h = bh & 15;
  int d = d2 & 63;
  bool im = d2 >= 64;
  float4 v;
  if (t < CCH) {
    const float* src = im ? c_im : c_re;
    v = *(const float4*)&src[(((size_t)b * CCH + t) * 16 + h) * 64 + d];
  } else {
    int col = colbase + (im ? (1024 + h*64 + d) : (h*64 + d));
    v = *(const float4*)&Cqkv[((size_t)b * 1024 + (t - CCH)) * 6144 + col];
  }
  if (Kp) {
    ushort4 o;
    o.x = f2bf(v.x); o.y = f2bf(v.y); o.z = f2bf(v.z); o.w = f2bf(v.w);
    *(ushort4*)&Kp[idx] = o;
  }
  float* dst = im ? out_im : out_re;
  *(float4*)&dst[(((size_t)b * 4096 + t) * 16 + h) * 64 + d] = v;
}

// ---------- pack V transposed via LDS: Vt[bh][d2][t] bf16 ----------
__global__ __launch_bounds__(256) void pack_vt_kernel(
    const float* __restrict__ Vc_re, const float* __restrict__ Vc_im,
    const float* __restrict__ Cqkv, unsigned short* __restrict__ Vt)
{
  __shared__ float Ts[64][136];
  const int ty = blockIdx.x & 63;   // t-tile
  const int bh = blockIdx.x >> 6;   // 0..31
  const int b = bh >> 4, h = bh & 15;
  const int t0 = ty * 64;
  const int tid = threadIdx.x;
#pragma unroll
  for (int rr = 0; rr < 8; rr++) {
    int j = rr * 256 + tid;
    int t_loc = j >> 5, c = j & 31;
    int d2 = c * 4;
    int t = t0 + t_loc;
    float4 v;
    if (t < CCH) {
      const float* src = (d2 < 64) ? Vc_re : Vc_im;
      int d = (d2 < 64) ? d2 : d2 - 64;
      v = *(const float4*)&src[(((size_t)b * CCH + t) * 16 + h) * 64 + d];
    } else {
      int col = 4096 + ((d2 < 64) ? (h*64 + d2) : (1024 + h*64 + d2 - 64));
      v = *(const float4*)&Cqkv[((size_t)b * 1024 + (t - CCH)) * 6144 + col];
    }
    *(float4*)&Ts[t_loc][d2] = v;
  }
  __syncthreads();
  const int d2 = tid >> 1, half = tid & 1;
  unsigned short tmp[32];
#pragma unroll
  for (int i = 0; i < 32; i++) tmp[i] = f2bf(Ts[half*32 + i][d2]);
  size_t dst = (size_t)bh * 128 * 4096 + (size_t)d2 * 4096 + t0 + half*32;
#pragma unroll
  for (int kq = 0; kq < 4; kq++)
    *(US8*)&Vt[dst + kq*8] = *(US8*)&tmp[kq*8];
}

// ---------- flash attention v3: 128 q-rows/block, t-range split over 2 blocks,
// global_load_lds double-buffered staging, XOR-swizzled LDS, partial outputs ----------
// Qp [bh][s][128] (pre-scaled 1/8), Kp [bh][t][128], Vt [bh][d2][t]
// Opart [tpar][bh][s][128] f32, Lpart [tpar][bh][s] f32
__global__ __launch_bounds__(256) void attn_kernel(
    const unsigned short* __restrict__ Qp, const unsigned short* __restrict__ Kp,
    const unsigned short* __restrict__ Vt, float* __restrict__ Opart,
    float* __restrict__ Lpart)
{
  const int bh   = blockIdx.x;   // 0..31  (linear id % 8 == bh % 8 -> XCD locality)
  const int sblk = blockIdx.y;   // 0..7
  const int tpar = blockIdx.z;   // 0..1
  const int s0 = sblk * 128;
  const int tid = threadIdx.x;
  const int lane = tid & 63, w = tid >> 6;
  const int l15 = lane & 15, q = lane >> 4;

  __shared__ alignas(16) unsigned short Ks[2][64][128];  // 32 KB, chunk-swizzled
  __shared__ alignas(16) unsigned short Vs[2][128][64];  // 32 KB, chunk-swizzled
  __shared__ alignas(16) unsigned short Ps[4][32][64];   // 16 KB, chunk-swizzled

  // persistent Q fragments: 2 m-frags x 4 k-chunks
  bf16x8 qf[2][4];
#pragma unroll
  for (int mi = 0; mi < 2; mi++) {
    const size_t qb = ((size_t)bh * 1024 + s0 + w*32 + mi*16 + l15) * 128;
#pragma unroll
    for (int kc = 0; kc < 4; kc++)
      qf[mi][kc] = *(const bf16x8*)&Qp[qb + kc*32 + q*8];
  }

  f32x4 oacc[2][8] = {};
  float lsum[2][4] = {};

  const size_t kpb = (size_t)bh * 4096 * 128;
  const size_t vtb = (size_t)bh * 128 * 4096;
  const int n_tiles = 2*sblk + 50;
  const int n_safe  = n_tiles - 2;

  // async staging: 1024 16B-chunks per K tile and per V tile; each wave does 4+4
  auto issue = [&](int buf, int t0) {
#pragma unroll
    for (int kk = 0; kk < 4; kk++) {
      int j = (w*4 + kk)*64 + lane;          // chunk index
      int r = j >> 4, p = j & 15, c = p ^ (r & 7);
      g2lds16(&Kp[kpb + (size_t)(t0 + r) * 128 + c*8],
              (unsigned short*)&Ks[buf][0][0] + (size_t)j * 8);
    }
#pragma unroll
    for (int kk = 0; kk < 4; kk++) {
      int j = (w*4 + kk)*64 + lane;
      int r = j >> 3, p = j & 7, c = p ^ (r & 7);
      g2lds16(&Vt[vtb + (size_t)r * 4096 + t0 + c*8],
              (unsigned short*)&Vs[buf][0][0] + (size_t)j * 8);
    }
  };

  int buf = 0;
  issue(0, tpar * 64);

  for (int it = tpar; it < n_tiles; it += 2) {
    __syncthreads();                       // drains loads for `buf`
    if (it + 2 < n_tiles) issue(buf ^ 1, (it + 2) * 64);   // overlap with compute

    // QK^T
    f32x4 sacc[2][4] = {};
#pragma unroll
    for (int kc = 0; kc < 4; kc++) {
      bf16x8 kf[4];
#pragma unroll
      for (int nc = 0; nc < 4; nc++)
        kf[nc] = *(const bf16x8*)&Ks[buf][nc*16 + l15][((kc*4 + q) ^ (l15 & 7)) * 8];
#pragma unroll
      for (int mi = 0; mi < 2; mi++)
#pragma unroll
        for (int nc = 0; nc < 4; nc++)
          sacc[mi][nc] = __builtin_amdgcn_mfma_f32_16x16x32_bf16(qf[mi][kc], kf[nc], sacc[mi][nc], 0, 0, 0);
    }

    // exp + P store (swizzled), mask only last 2 tiles
    const bool safe = (it < n_safe);
    const int t0 = it << 6;
#pragma unroll
    for (int mi = 0; mi < 2; mi++)
#pragma unroll
      for (int r = 0; r < 4; r++) {
        const int rr = mi*16 + q*4 + r;
        const int rel = s0 + w*32 + rr + CCH - t0;
        float ls = 0.f;
#pragma unroll
        for (int nc = 0; nc < 4; nc++) {
          float p = __expf(sacc[mi][nc][r]);
          if (!safe && (nc*16 + l15 > rel)) p = 0.f;
          ls += p;
          int cch = ((nc*2 + (l15 >> 3)) ^ (rr & 7));
          Ps[w][rr][cch*8 + (l15 & 7)] = f2bf_cvt(p);
        }
        lsum[mi][r] += ls;
      }

    // PV
#pragma unroll
    for (int kch = 0; kch < 2; kch++) {
      bf16x8 pf[2];
#pragma unroll
      for (int mi = 0; mi < 2; mi++) {
        int rr = mi*16 + l15;
        pf[mi] = *(const bf16x8*)&Ps[w][rr][((kch*4 + q) ^ (rr & 7)) * 8];
      }
#pragma unroll
      for (int dc = 0; dc < 8; dc++) {
        int d2 = dc*16 + l15;
        bf16x8 vfr = *(const bf16x8*)&Vs[buf][d2][((kch*4 + q) ^ (l15 & 7)) * 8];
#pragma unroll
        for (int mi = 0; mi < 2; mi++)
          oacc[mi][dc] = __builtin_amdgcn_mfma_f32_16x16x32_bf16(pf[mi], vfr, oacc[mi][dc], 0, 0, 0);
      }
    }
    buf ^= 1;
  }

  // write partials
  const size_t pb = ((size_t)tpar * 32 + bh) * 1024 + s0 + w*32;
#pragma unroll
  for (int mi = 0; mi < 2; mi++)
#pragma unroll
    for (int r = 0; r < 4; r++) {
      float l = lsum[mi][r];
      l += __shfl_xor(l, 1, 64);
      l += __shfl_xor(l, 2, 64);
      l += __shfl_xor(l, 4, 64);
      l += __shfl_xor(l, 8, 64);
      if (l15 == 0) Lpart[pb + mi*16 + q*4 + r] = l;
    }
#pragma unroll
  for (int mi = 0; mi < 2; mi++)
#pragma unroll
    for (int dc = 0; dc < 8; dc++)
#pragma unroll
      for (int r = 0; r < 4; r++)
        Opart[(pb + mi*16 + q*4 + r) * 128 + dc*16 + l15] = oacc[mi][dc][r];
}

// ---------- combine partials -> Ao bf16 [m][2048] ----------
__global__ __launch_bounds__(256) void attn_combine_kernel(
    const float* __restrict__ Opart, const float* __restrict__ Lpart,
    unsigned short* __restrict__ Ao)
{
  const size_t TS = 4194304ull;   // tpar stride in floats (32*1024*128)
  int gid = blockIdx.x * 256 + threadIdx.x;
  int idx = gid * 8;              // over 2048*2048
  int m = idx >> 11, n0 = idx & 2047;
  int b = m >> 10, s = m & 1023;
  int h, d2_0;
  if (n0 < 1024) { h = n0 >> 6; d2_0 = n0 & 63; }
  else { h = (n0 - 1024) >> 6; d2_0 = 64 + ((n0 - 1024) & 63); }
  int bh = b*16 + h;
  size_t ob = ((size_t)bh * 1024 + s) * 128 + d2_0;
  float l0 = Lpart[(size_t)bh * 1024 + s];
  float l1 = Lpart[TS/128 + (size_t)bh * 1024 + s];   // Lpart tpar stride = 32*1024
  float inv = 1.f / (l0 + l1);
  float4 x0 = *(const float4*)&Opart[ob];
  float4 x1 = *(const float4*)&Opart[ob + 4];
  float4 y0 = *(const float4*)&Opart[ob + TS];
  float4 y1 = *(const float4*)&Opart[ob + TS + 4];
  US8 o;
  o.u[0] = f2bf((x0.x + y0.x) * inv); o.u[1] = f2bf((x0.y + y0.y) * inv);
  o.u[2] = f2bf((x0.z + y0.z) * inv); o.u[3] = f2bf((x0.w + y0.w) * inv);
  o.u[4] = f2bf((x1.x + y1.x) * inv); o.u[5] = f2bf((x1.y + y1.y) * inv);
  o.u[6] = f2bf((x1.z + y1.z) * inv); o.u[7] = f2bf((x1.w + y1.w) * inv);
  *(US8*)&Ao[idx] = o;
}

// ---------- launch ----------
extern "C" void kernel_launch(void* const* d_in, const int* in_sizes, int n_in,
                              void* d_out, int out_size, void* d_ws, size_t ws_size,
                              hipStream_t stream)
{
  (void)in_sizes; (void)n_in; (void)out_size; (void)ws_size;
  const float* hre = (const float*)d_in[0];
  const float* him = (const float*)d_in[1];
  const float* Kcr = (const float*)d_in[2];
  const float* Kci = (const float*)d_in[3];
  const float* Vcr = (const float*)d_in[4];
  const float* Vci = (const float*)d_in[5];
  const float* gamma = (const float*)d_in[6];
  const float* bre = (const float*)d_in[7];
  const float* bim = (const float*)d_in[8];
  const float* qWr = (const float*)d_in[9];
  const float* qWi = (const float*)d_in[10];
  const float* qbr = (const float*)d_in[11];
  const float* qbi = (const float*)d_in[12];
  const float* kWr = (const float*)d_in[13];
  const float* kWi = (const float*)d_in[14];
  const float* kbr = (const float*)d_in[15];
  const float* kbi = (const float*)d_in[16];
  const float* vWr = (const float*)d_in[17];
  const float* vWi = (const float*)d_in[18];
  const float* vbr = (const float*)d_in[19];
  const float* vbi = (const float*)d_in[20];
  const float* oWr = (const float*)d_in[21];
  const float* oWi = (const float*)d_in[22];
  const float* obr = (const float*)d_in[23];
  const float* obi = (const float*)d_in[24];
  float* out = (float*)d_out;

  char* ws = (char*)d_ws;
  size_t off = 0;
  auto carve = [&](size_t bytes) {
    char* p = ws + off;
    off += (bytes + 255) & ~(size_t)255;
    return p;
  };
  unsigned short* Aln = (unsigned short*)carve(2048ull * 2048 * 2);       // 8 MB
  unsigned short* Wc  = (unsigned short*)carve(4ull * 2048 * 2048 * 2);   // 32 MB
  float*          bc  = (float*)carve(4ull * 2048 * 4);                   // 32 KB
  float*          Cqkv= (float*)carve(2048ull * 6144 * 4);                // 48 MB
  unsigned short* Qp  = (unsigned short*)carve(4194304ull * 2);           // 8 MB
  unsigned short* Kp  = (unsigned short*)carve(16777216ull * 2);          // 32 MB
  unsigned short* Vt  = (unsigned short*)carve(16777216ull * 2);          // 32 MB
  unsigned short* Ao  = (unsigned short*)carve(2048ull * 2048 * 2);       // 8 MB

  // Opart/Lpart overlay regions no longer live at attn time:
  float* Opart = (float*)Cqkv;   // 33.6 MB <= 48 MB; Cqkv last read by pack_vt (pre-attn)
  float* Lpart = (float*)Aln;    // 256 KB  <= 8 MB;  Aln last read by gemm_bt

  // output chunk offsets (floats)
  float* out_Kre = out + 4194304;
  float* out_Kim = out + 4194304 + 8388608;
  float* out_Vre = out + 4194304 + 2 * 8388608;
  float* out_Vim = out + 4194304 + 3 * 8388608;

  hipLaunchKernelGGL(ln_kernel, dim3(2048), dim3(256), 0, stream,
                     hre, him, gamma, bre, bim, Aln);
  hipLaunchKernelGGL(wprep_kernel, dim3(8192), dim3(256), 0, stream,
                     qWr, qWi, kWr, kWi, vWr, vWi, oWr, oWi, Wc);
  hipLaunchKernelGGL(bprep_kernel, dim3(32), dim3(256), 0, stream,
                     qbr, qbi, kbr, kbi, vbr, vbi, obr, obi, bc);
  hipLaunchKernelGGL(gemm_bt_kernel, dim3(48, 16), dim3(256), 0, stream,
                     Aln, Wc, bc, Cqkv, 6144, 2048);
  hipLaunchKernelGGL(pack_q_kernel, dim3(4096), dim3(256), 0, stream, Cqkv, Qp);
  hipLaunchKernelGGL(pack_kv_kernel, dim3(16384), dim3(256), 0, stream,
                     Kcr, Kci, Cqkv, 2048, Kp, out_Kre, out_Kim);
  hipLaunchKernelGGL(pack_kv_kernel, dim3(16384), dim3(256), 0, stream,
                     Vcr, Vci, Cqkv, 4096, (unsigned short*)nullptr, out_Vre, out_Vim);
  hipLaunchKernelGGL(pack_vt_kernel, dim3(2048), dim3(256), 0, stream,
                     Vcr, Vci, Cqkv, Vt);
  hipLaunchKernelGGL(attn_kernel, dim3(32, 8, 2), dim3(256), 0, stream,
                     Qp, Kp, Vt, Opart, Lpart);
  hipLaunchKernelGGL(attn_combine_kernel, dim3(2048), dim3(256), 0, stream,
                     Opart, Lpart, Ao);
  hipLaunchKernelGGL(gemm_oproj_kernel, dim3(16, 16), dim3(256), 0, stream,
                     Ao, Wc + 3ull * 2048 * 2048, bc + 3 * 2048, hre, him, out);
}

// Round 2
// 601.616 us; speedup vs baseline: 1.0145x; 1.0138x over previous
//
#include <hip/hip_runtime.h>
#include <hip/hip_bf16.h>
#include <cstdint>
#include <cstddef>

// ---------- types ----------
typedef __bf16 bf16x8 __attribute__((ext_vector_type(8)));
typedef float  f32x4  __attribute__((ext_vector_type(4)));

__device__ __forceinline__ unsigned short f2bf(float f) {
  union { float f; unsigned u; } v; v.f = f;
  unsigned u = v.u;
  u += 0x7FFFu + ((u >> 16) & 1u);   // RNE
  return (unsigned short)(u >> 16);
}

// native cast path: compiler emits v_cvt_pk_bf16_f32 (RNE, same rounding as f2bf)
__device__ __forceinline__ unsigned short f2bf_cvt(float f) {
  __bf16 h = (__bf16)f;
  return __builtin_bit_cast(unsigned short, h);
}

struct alignas(16) US8 { unsigned short u[8]; };

__device__ __forceinline__ void g2lds16(const void* g, void* l) {
  __builtin_amdgcn_global_load_lds(
      (const __attribute__((address_space(1))) unsigned int*)g,
      (__attribute__((address_space(3))) unsigned int*)l, 16, 0, 0);
}

// sizes
#define BB 2
#define SS 1024
#define HID 1024
#define NHH 16
#define HDD 64
#define TT 4096
#define CCH 3072
// Q pre-scale: 1/sqrt(64) * log2(e)  (scores then exponentiated with raw v_exp_f32 = 2^x)
#define QSCALE (0.125f * 1.44269504088896f)

// ---------- LayerNorm (complex) -> Aln bf16 [2048][2048] = [nr | ni] ----------
__global__ __launch_bounds__(256) void ln_kernel(
    const float* __restrict__ hre, const float* __restrict__ him,
    const float* __restrict__ gamma, const float* __restrict__ bre,
    const float* __restrict__ bim, unsigned short* __restrict__ Aln)
{
  int m = blockIdx.x;
  int tid = threadIdx.x;
  const float4 vr = ((const float4*)(hre + (size_t)m * HID))[tid];
  const float4 vi = ((const float4*)(him + (size_t)m * HID))[tid];
  float sr = vr.x + vr.y + vr.z + vr.w;
  float si = vi.x + vi.y + vi.z + vi.w;
  float sq = vr.x*vr.x + vr.y*vr.y + vr.z*vr.z + vr.w*vr.w
           + vi.x*vi.x + vi.y*vi.y + vi.z*vi.z + vi.w*vi.w;
  __shared__ float red[3][4];
  int lane = tid & 63, w = tid >> 6;
  for (int off = 32; off; off >>= 1) {
    sr += __shfl_down(sr, off, 64);
    si += __shfl_down(si, off, 64);
    sq += __shfl_down(sq, off, 64);
  }
  if (lane == 0) { red[0][w] = sr; red[1][w] = si; red[2][w] = sq; }
  __syncthreads();
  sr = red[0][0] + red[0][1] + red[0][2] + red[0][3];
  si = red[1][0] + red[1][1] + red[1][2] + red[1][3];
  sq = red[2][0] + red[2][1] + red[2][2] + red[2][3];
  float mur = sr * (1.f/1024.f), mui = si * (1.f/1024.f);
  float var = sq * (1.f/1024.f) - mur*mur - mui*mui;
  float inv = rsqrtf(var + 1e-5f);
  int k = tid * 4;
  float4 g  = ((const float4*)gamma)[tid];
  float4 br = ((const float4*)bre)[tid];
  float4 bi = ((const float4*)bim)[tid];
  ushort4 nr, ni;
  nr.x = f2bf((vr.x - mur) * inv * g.x + br.x);
  nr.y = f2bf((vr.y - mur) * inv * g.y + br.y);
  nr.z = f2bf((vr.z - mur) * inv * g.z + br.z);
  nr.w = f2bf((vr.w - mur) * inv * g.w + br.w);
  ni.x = f2bf((vi.x - mui) * inv * g.x + bi.x);
  ni.y = f2bf((vi.y - mui) * inv * g.y + bi.y);
  ni.z = f2bf((vi.z - mui) * inv * g.z + bi.z);
  ni.w = f2bf((vi.w - mui) * inv * g.w + bi.w);
  *(ushort4*)&Aln[(size_t)m * 2048 + k]        = nr;
  *(ushort4*)&Aln[(size_t)m * 2048 + 1024 + k] = ni;
}

// ---------- combined weights: Wc[p][n][k] bf16, p in {q,k,v,o}, 2048x2048 each ----------
__global__ __launch_bounds__(256) void wprep_kernel(
    const float* __restrict__ qWr, const float* __restrict__ qWi,
    const float* __restrict__ kWr, const float* __restrict__ kWi,
    const float* __restrict__ vWr, const float* __restrict__ vWi,
    const float* __restrict__ oWr, const float* __restrict__ oWi,
    unsigned short* __restrict__ Wc)
{
  int gid = blockIdx.x * 256 + threadIdx.x;
  int idx = gid * 8;                     // over 4*2048*2048
  int p   = idx >> 22;
  int rem = idx & 0x3FFFFF;
  int n   = rem >> 11;
  int k   = rem & 2047;
  const float* Wr; const float* Wi;
  switch (p) {
    case 0:  Wr = qWr; Wi = qWi; break;
    case 1:  Wr = kWr; Wi = kWi; break;
    case 2:  Wr = vWr; Wi = vWi; break;
    default: Wr = oWr; Wi = oWi; break;
  }
  const float* src; float sgn = 1.f;
  if (n < 1024) {
    if (k < 1024) src = Wr + (size_t)n * 1024 + k;
    else        { src = Wi + (size_t)n * 1024 + (k - 1024); sgn = -1.f; }
  } else {
    if (k < 1024) src = Wi + (size_t)(n - 1024) * 1024 + k;
    else          src = Wr + (size_t)(n - 1024) * 1024 + (k - 1024);
  }
  float4 a = ((const float4*)src)[0];
  float4 b = ((const float4*)src)[1];
  US8 o;
  o.u[0] = f2bf(a.x * sgn); o.u[1] = f2bf(a.y * sgn);
  o.u[2] = f2bf(a.z * sgn); o.u[3] = f2bf(a.w * sgn);
  o.u[4] = f2bf(b.x * sgn); o.u[5] = f2bf(b.y * sgn);
  o.u[6] = f2bf(b.z * sgn); o.u[7] = f2bf(b.w * sgn);
  *(US8*)&Wc[idx] = o;
}

__global__ __launch_bounds__(256) void bprep_kernel(
    const float* __restrict__ qbr, const float* __restrict__ qbi,
    const float* __restrict__ kbr, const float* __restrict__ kbi,
    const float* __restrict__ vbr, const float* __restrict__ vbi,
    const float* __restrict__ obr, const float* __restrict__ obi,
    float* __restrict__ bc)
{
  int idx = blockIdx.x * 256 + threadIdx.x;  // 8192
  int p = idx >> 11, n = idx & 2047;
  const float* br; const float* bi;
  switch (p) {
    case 0:  br = qbr; bi = qbi; break;
    case 1:  br = kbr; bi = kbi; break;
    case 2:  br = vbr; bi = vbi; break;
    default: br = obr; bi = obi; break;
  }
  bc[idx] = (n < 1024) ? br[n] : bi[n - 1024];
}

// ---------- QKV GEMM: A[2048 x 2048] * Wc[6144 x 2048]^T + bias ----------
// Epilogue routes per column section directly into attention-ready buffers:
//   sec 0 (Q): Qp bf16 [bh][s][128], scaled by QSCALE
//   sec 1 (K): Kp bf16 [bh][3072+s][128]  +  out_K f32 [b][3072+s][h][d]
//   sec 2 (V): out_V f32 [b][3072+s][h][d]
// This removes the Cqkv f32 intermediate (48 MB write + 48 MB re-read).
__global__ __launch_bounds__(256) void gemm_qkv_kernel(
    const unsigned short* __restrict__ A, const unsigned short* __restrict__ Bm,
    const float* __restrict__ bias,
    unsigned short* __restrict__ Qp, unsigned short* __restrict__ Kp,
    float* __restrict__ out_Kre, float* __restrict__ out_Kim,
    float* __restrict__ out_Vre, float* __restrict__ out_Vim)
{
  __shared__ alignas(16) unsigned short As[128][32];
  __shared__ alignas(16) unsigned short Bs[128][32];
  const int K = 2048;
  int bm = blockIdx.y * 128;
  int bn = blockIdx.x * 128;
  int tid = threadIdx.x;
  int lane = tid & 63, w = tid >> 6;
  int wm = (w >> 1) * 64, wn = (w & 1) * 64;
  int l15 = lane & 15, q = lane >> 4;
  int lr = tid >> 2;            // 0..63
  int lc = (tid & 3) * 8;       // 0,8,16,24

  f32x4 acc[4][4] = {};

  for (int k0 = 0; k0 < K; k0 += 32) {
    g2lds16(&A [(size_t)(bm + lr)      * K + k0 + lc], (unsigned short*)As + 8*tid);
    g2lds16(&A [(size_t)(bm + lr + 64) * K + k0 + lc], (unsigned short*)As + 2048 + 8*tid);
    g2lds16(&Bm[(size_t)(bn + lr)      * K + k0 + lc], (unsigned short*)Bs + 8*tid);
    g2lds16(&Bm[(size_t)(bn + lr + 64) * K + k0 + lc], (unsigned short*)Bs + 2048 + 8*tid);
    __syncthreads();
    bf16x8 af[4], bfr[4];
#pragma unroll
    for (int i = 0; i < 4; i++) af[i]  = *(const bf16x8*)&As[wm + i*16 + l15][q*8];
#pragma unroll
    for (int i = 0; i < 4; i++) bfr[i] = *(const bf16x8*)&Bs[wn + i*16 + l15][q*8];
#pragma unroll
    for (int i = 0; i < 4; i++)
#pragma unroll
      for (int j = 0; j < 4; j++)
        acc[i][j] = __builtin_amdgcn_mfma_f32_16x16x32_bf16(af[i], bfr[j], acc[i][j], 0, 0, 0);
    __syncthreads();
  }

  const int sec = bn >> 11;   // 0=Q, 1=K, 2=V (uniform per block; 2048 % 128 == 0)
#pragma unroll
  for (int i = 0; i < 4; i++)
#pragma unroll
    for (int j = 0; j < 4; j++) {
      int n = bn + wn + j*16 + l15;
      float bv = bias[n];
      int col = n & 2047;
      int re = (col < 1024) ? 1 : 0;
      int h = (col & 1023) >> 6, d = col & 63;
      int d2 = re ? d : 64 + d;
#pragma unroll
      for (int r = 0; r < 4; r++) {
        int m = bm + wm + i*16 + q*4 + r;
        float val = acc[i][j][r] + bv;
        int b = m >> 10, s = m & 1023;
        int bh = b*16 + h;
        if (sec == 0) {
          Qp[((size_t)bh*1024 + s)*128 + d2] = f2bf(val * QSCALE);
        } else if (sec == 1) {
          int t = CCH + s;
          Kp[((size_t)bh*4096 + t)*128 + d2] = f2bf(val);
          float* dst = re ? out_Kre : out_Kim;
          dst[(((size_t)b*4096 + t)*16 + h)*64 + d] = val;
        } else {
          int t = CCH + s;
          float* dst = re ? out_Vre : out_Vim;
          dst[(((size_t)b*4096 + t)*16 + h)*64 + d] = val;
        }
      }
    }
}

// ---------- o-proj GEMM with residual + split write to out_re/out_im ----------
__global__ __launch_bounds__(256) void gemm_oproj_kernel(
    const unsigned short* __restrict__ A, const unsigned short* __restrict__ Bm,
    const float* __restrict__ bias, const float* __restrict__ hre,
    const float* __restrict__ him, float* __restrict__ out)
{
  __shared__ alignas(16) unsigned short As[128][32];
  __shared__ alignas(16) unsigned short Bs[128][32];
  int bm = blockIdx.y * 128;
  int bn = blockIdx.x * 128;
  int tid = threadIdx.x;
  int lane = tid & 63, w = tid >> 6;
  int wm = (w >> 1) * 64, wn = (w & 1) * 64;
  int l15 = lane & 15, q = lane >> 4;
  int lr = tid >> 2;
  int lc = (tid & 3) * 8;
  const int K = 2048;

  f32x4 acc[4][4] = {};

  for (int k0 = 0; k0 < K; k0 += 32) {
    g2lds16(&A [(size_t)(bm + lr)      * K + k0 + lc], (unsigned short*)As + 8*tid);
    g2lds16(&A [(size_t)(bm + lr + 64) * K + k0 + lc], (unsigned short*)As + 2048 + 8*tid);
    g2lds16(&Bm[(size_t)(bn + lr)      * K + k0 + lc], (unsigned short*)Bs + 8*tid);
    g2lds16(&Bm[(size_t)(bn + lr + 64) * K + k0 + lc], (unsigned short*)Bs + 2048 + 8*tid);
    __syncthreads();
    bf16x8 af[4], bfr[4];
#pragma unroll
    for (int i = 0; i < 4; i++) af[i]  = *(const bf16x8*)&As[wm + i*16 + l15][q*8];
#pragma unroll
    for (int i = 0; i < 4; i++) bfr[i] = *(const bf16x8*)&Bs[wn + i*16 + l15][q*8];
#pragma unroll
    for (int i = 0; i < 4; i++)
#pragma unroll
      for (int j = 0; j < 4; j++)
        acc[i][j] = __builtin_amdgcn_mfma_f32_16x16x32_bf16(af[i], bfr[j], acc[i][j], 0, 0, 0);
    __syncthreads();
  }

#pragma unroll
  for (int i = 0; i < 4; i++)
#pragma unroll
    for (int j = 0; j < 4; j++) {
      int n = bn + wn + j*16 + l15;
      float bv = bias[n];
#pragma unroll
      for (int r = 0; r < 4; r++) {
        int m = bm + wm + i*16 + q*4 + r;
        float val = acc[i][j][r] + bv;
        if (n < 1024) out[(size_t)m * 1024 + n] = val + hre[(size_t)m * 1024 + n];
        else out[2097152 + (size_t)m * 1024 + (n - 1024)] = val + him[(size_t)m * 1024 + (n - 1024)];
      }
    }
}

// ---------- K cache part: cache -> Kp bf16 [bh][t<3072][128] + out_K f32 ----------
__global__ __launch_bounds__(256) void pack_kcache_kernel(
    const float* __restrict__ c_re, const float* __restrict__ c_im,
    unsigned short* __restrict__ Kp,
    float* __restrict__ out_re, float* __restrict__ out_im)
{
  int bh = blockIdx.y;              // 0..31
  int idx = (blockIdx.x * 256 + threadIdx.x) * 4;  // over 3072*128
  int d2 = idx & 127;
  int t  = idx >> 7;                // 0..3071
  int b = bh >> 4, h = bh & 15;
  int d = d2 & 63;
  bool im = d2 >= 64;
  const float* src = im ? c_im : c_re;
  float4 v = *(const float4*)&src[(((size_t)b * CCH + t) * 16 + h) * 64 + d];
  ushort4 o;
  o.x = f2bf(v.x); o.y = f2bf(v.y); o.z = f2bf(v.z); o.w = f2bf(v.w);
  *(ushort4*)&Kp[((size_t)bh * 4096 + t) * 128 + d2] = o;
  float* dst = im ? out_im : out_re;
  *(float4*)&dst[(((size_t)b * 4096 + t) * 16 + h) * 64 + d] = v;
}

// ---------- fused V: cache -> out_V f32 (+readback of new part) -> Vt bf16 [bh][d2][t] ----------
__global__ __launch_bounds__(256) void pack_vt_fused_kernel(
    const float* __restrict__ Vc_re, const float* __restrict__ Vc_im,
    float* __restrict__ out_Vre, float* __restrict__ out_Vim,
    unsigned short* __restrict__ Vt)
{
  __shared__ float Ts[64][136];
  const int ty = blockIdx.x & 63;   // t-tile
  const int bh = blockIdx.x >> 6;   // 0..31
  const int b = bh >> 4, h = bh & 15;
  const int t0 = ty * 64;
  const int tid = threadIdx.x;
#pragma unroll
  for (int rr = 0; rr < 8; rr++) {
    int j = rr * 256 + tid;
    int t_loc = j >> 5, c = j & 31;
    int d2 = c * 4;
    int t = t0 + t_loc;
    int d = (d2 < 64) ? d2 : d2 - 64;
    float4 v;
    if (t < CCH) {
      const float* src = (d2 < 64) ? Vc_re : Vc_im;
      v = *(const float4*)&src[(((size_t)b * CCH + t) * 16 + h) * 64 + d];
      float* dst = (d2 < 64) ? out_Vre : out_Vim;
      *(float4*)&dst[(((size_t)b * 4096 + t) * 16 + h) * 64 + d] = v;
    } else {
      const float* src = (d2 < 64) ? out_Vre : out_Vim;   // written by gemm_qkv
      v = *(const float4*)&src[(((size_t)b * 4096 + t) * 16 + h) * 64 + d];
    }
    *(float4*)&Ts[t_loc][d2] = v;
  }
  __syncthreads();
  const int d2 = tid >> 1, half = tid & 1;
  unsigned short tmp[32];
#pragma unroll
  for (int i = 0; i < 32; i++) tmp[i] = f2bf(Ts[half*32 + i][d2]);
  size_t dst = (size_t)bh * 128 * 4096 + (size_t)d2 * 4096 + t0 + half*32;
#pragma unroll
  for (int kq = 0; kq < 4; kq++)
    *(US8*)&Vt[dst + kq*8] = *(US8*)&tmp[kq*8];
}

// ---------- flash attention: 128 q-rows/block, t-range split over 2 blocks ----------
// Qp [bh][s][128] (pre-scaled QSCALE), Kp [bh][t][128], Vt [bh][d2][t]
// Opart [tpar][bh][s][128] f32, Lpart [tpar][bh][s] f32
// Ps swizzle S(rr) = ((rr>>2)&3)<<1 | (rr&1): writes hit 8 distinct 16B chunks
// across (q,hi) -> conflict-free; pf reads stay 2-way (free).
__global__ __launch_bounds__(256) void attn_kernel(
    const unsigned short* __restrict__ Qp, const unsigned short* __restrict__ Kp,
    const unsigned short* __restrict__ Vt, float* __restrict__ Opart,
    float* __restrict__ Lpart)
{
  const int bh   = blockIdx.x;   // 0..31
  const int sblk = blockIdx.y;   // 0..7
  const int tpar = blockIdx.z;   // 0..1
  const int s0 = sblk * 128;
  const int tid = threadIdx.x;
  const int lane = tid & 63, w = tid >> 6;
  const int l15 = lane & 15, q = lane >> 4;

  __shared__ alignas(16) unsigned short Ks[2][64][128];  // 32 KB
  __shared__ alignas(16) unsigned short Vs[2][128][64];  // 32 KB
  __shared__ alignas(16) unsigned short Ps[4][32][64];   // 16 KB

  // persistent Q fragments: 2 m-frags x 4 k-chunks
  bf16x8 qf[2][4];
#pragma unroll
  for (int mi = 0; mi < 2; mi++) {
    const size_t qb = ((size_t)bh * 1024 + s0 + w*32 + mi*16 + l15) * 128;
#pragma unroll
    for (int kc = 0; kc < 4; kc++)
      qf[mi][kc] = *(const bf16x8*)&Qp[qb + kc*32 + q*8];
  }

  f32x4 oacc[2][8] = {};
  float lsum[2][4] = {};

  const size_t kpb = (size_t)bh * 4096 * 128;
  const size_t vtb = (size_t)bh * 128 * 4096;
  const int n_tiles = 2*sblk + 50;
  const int n_safe  = n_tiles - 2;

  auto issue = [&](int buf, int t0) {
#pragma unroll
    for (int kk = 0; kk < 4; kk++) {
      int j = (w*4 + kk)*64 + lane;          // chunk index
      int r = j >> 4, p = j & 15, c = p ^ (r & 7);
      g2lds16(&Kp[kpb + (size_t)(t0 + r) * 128 + c*8],
              (unsigned short*)&Ks[buf][0][0] + (size_t)j * 8);
    }
#pragma unroll
    for (int kk = 0; kk < 4; kk++) {
      int j = (w*4 + kk)*64 + lane;
      int r = j >> 3, p = j & 7, c = p ^ (r & 7);
      g2lds16(&Vt[vtb + (size_t)r * 4096 + t0 + c*8],
              (unsigned short*)&Vs[buf][0][0] + (size_t)j * 8);
    }
  };

  int buf = 0;
  issue(0, tpar * 64);

  for (int it = tpar; it < n_tiles; it += 2) {
    __syncthreads();                       // drains loads for `buf`
    if (it + 2 < n_tiles) issue(buf ^ 1, (it + 2) * 64);   // overlap with compute

    // QK^T
    f32x4 sacc[2][4] = {};
    __builtin_amdgcn_s_setprio(1);
#pragma unroll
    for (int kc = 0; kc < 4; kc++) {
      bf16x8 kf[4];
#pragma unroll
      for (int nc = 0; nc < 4; nc++)
        kf[nc] = *(const bf16x8*)&Ks[buf][nc*16 + l15][((kc*4 + q) ^ (l15 & 7)) * 8];
#pragma unroll
      for (int mi = 0; mi < 2; mi++)
#pragma unroll
        for (int nc = 0; nc < 4; nc++)
          sacc[mi][nc] = __builtin_amdgcn_mfma_f32_16x16x32_bf16(qf[mi][kc], kf[nc], sacc[mi][nc], 0, 0, 0);
    }
    __builtin_amdgcn_s_setprio(0);

    // exp2 + P store (conflict-free swizzle), mask only last 2 tiles
    const bool safe = (it < n_safe);
    const int t0 = it << 6;
#pragma unroll
    for (int mi = 0; mi < 2; mi++)
#pragma unroll
      for (int r = 0; r < 4; r++) {
        const int rr = mi*16 + q*4 + r;
        const int rel = s0 + w*32 + rr + CCH - t0;
        float ls = 0.f;
#pragma unroll
        for (int nc = 0; nc < 4; nc++) {
          float p;
          asm("v_exp_f32 %0, %1" : "=v"(p) : "v"(sacc[mi][nc][r]));   // 2^x; log2e folded into Qp
          if (!safe && (nc*16 + l15 > rel)) p = 0.f;
          ls += p;
          int cch = (nc*2 + (l15 >> 3)) ^ ((q << 1) | (r & 1));
          Ps[w][rr][cch*8 + (l15 & 7)] = f2bf_cvt(p);
        }
        lsum[mi][r] += ls;
      }

    // PV
#pragma unroll
    for (int kch = 0; kch < 2; kch++) {
      bf16x8 pf[2];
#pragma unroll
      for (int mi = 0; mi < 2; mi++) {
        int rr = mi*16 + l15;
        int sw = (((l15 >> 2) & 3) << 1) | (l15 & 1);
        pf[mi] = *(const bf16x8*)&Ps[w][rr][((kch*4 + q) ^ sw) * 8];
      }
      __builtin_amdgcn_s_setprio(1);
#pragma unroll
      for (int dc = 0; dc < 8; dc++) {
        int d2 = dc*16 + l15;
        bf16x8 vfr = *(const bf16x8*)&Vs[buf][d2][((kch*4 + q) ^ (l15 & 7)) * 8];
#pragma unroll
        for (int mi = 0; mi < 2; mi++)
          oacc[mi][dc] = __builtin_amdgcn_mfma_f32_16x16x32_bf16(pf[mi], vfr, oacc[mi][dc], 0, 0, 0);
      }
      __builtin_amdgcn_s_setprio(0);
    }
    buf ^= 1;
  }

  // write partials
  const size_t pb = ((size_t)tpar * 32 + bh) * 1024 + s0 + w*32;
#pragma unroll
  for (int mi = 0; mi < 2; mi++)
#pragma unroll
    for (int r = 0; r < 4; r++) {
      float l = lsum[mi][r];
      l += __shfl_xor(l, 1, 64);
      l += __shfl_xor(l, 2, 64);
      l += __shfl_xor(l, 4, 64);
      l += __shfl_xor(l, 8, 64);
      if (l15 == 0) Lpart[pb + mi*16 + q*4 + r] = l;
    }
#pragma unroll
  for (int mi = 0; mi < 2; mi++)
#pragma unroll
    for (int dc = 0; dc < 8; dc++)
#pragma unroll
      for (int r = 0; r < 4; r++)
        Opart[(pb + mi*16 + q*4 + r) * 128 + dc*16 + l15] = oacc[mi][dc][r];
}

// ---------- combine partials -> Ao bf16 [m][2048] ----------
__global__ __launch_bounds__(256) void attn_combine_kernel(
    const float* __restrict__ Opart, const float* __restrict__ Lpart,
    unsigned short* __restrict__ Ao)
{
  const size_t TS = 4194304ull;   // tpar stride in floats (32*1024*128)
  int gid = blockIdx.x * 256 + threadIdx.x;
  int idx = gid * 8;              // over 2048*2048
  int m = idx >> 11, n0 = idx & 2047;
  int b = m >> 10, s = m & 1023;
  int h, d2_0;
  if (n0 < 1024) { h = n0 >> 6; d2_0 = n0 & 63; }
  else { h = (n0 - 1024) >> 6; d2_0 = 64 + ((n0 - 1024) & 63); }
  int bh = b*16 + h;
  size_t ob = ((size_t)bh * 1024 + s) * 128 + d2_0;
  float l0 = Lpart[(size_t)bh * 1024 + s];
  float l1 = Lpart[32768 + (size_t)bh * 1024 + s];
  float inv = 1.f / (l0 + l1);
  float4 x0 = *(const float4*)&Opart[ob];
  float4 x1 = *(const float4*)&Opart[ob + 4];
  float4 y0 = *(const float4*)&Opart[ob + TS];
  float4 y1 = *(const float4*)&Opart[ob + TS + 4];
  US8 o;
  o.u[0] = f2bf((x0.x + y0.x) * inv); o.u[1] = f2bf((x0.y + y0.y) * inv);
  o.u[2] = f2bf((x0.z + y0.z) * inv); o.u[3] = f2bf((x0.w + y0.w) * inv);
  o.u[4] = f2bf((x1.x + y1.x) * inv); o.u[5] = f2bf((x1.y + y1.y) * inv);
  o.u[6] = f2bf((x1.z + y1.z) * inv); o.u[7] = f2bf((x1.w + y1.w) * inv);
  *(US8*)&Ao[idx] = o;
}

// ---------- launch ----------
extern "C" void kernel_launch(void* const* d_in, const int* in_sizes, int n_in,
                              void* d_out, int out_size, void* d_ws, size_t ws_size,
                              hipStream_t stream)
{
  (void)in_sizes; (void)n_in; (void)out_size; (void)ws_size;
  const float* hre = (const float*)d_in[0];
  const float* him = (const float*)d_in[1];
  const float* Kcr = (const float*)d_in[2];
  const float* Kci = (const float*)d_in[3];
  const float* Vcr = (const float*)d_in[4];
  const float* Vci = (const float*)d_in[5];
  const float* gamma = (const float*)d_in[6];
  const float* bre = (const float*)d_in[7];
  const float* bim = (const float*)d_in[8];
  const float* qWr = (const float*)d_in[9];
  const float* qWi = (const float*)d_in[10];
  const float* qbr = (const float*)d_in[11];
  const float* qbi = (const float*)d_in[12];
  const float* kWr = (const float*)d_in[13];
  const float* kWi = (const float*)d_in[14];
  const float* kbr = (const float*)d_in[15];
  const float* kbi = (const float*)d_in[16];
  const float* vWr = (const float*)d_in[17];
  const float* vWi = (const float*)d_in[18];
  const float* vbr = (const float*)d_in[19];
  const float* vbi = (const float*)d_in[20];
  const float* oWr = (const float*)d_in[21];
  const float* oWi = (const float*)d_in[22];
  const float* obr = (const float*)d_in[23];
  const float* obi = (const float*)d_in[24];
  float* out = (float*)d_out;

  char* ws = (char*)d_ws;
  size_t off = 0;
  auto carve = [&](size_t bytes) {
    char* p = ws + off;
    off += (bytes + 255) & ~(size_t)255;
    return p;
  };
  unsigned short* Aln  = (unsigned short*)carve(2048ull * 2048 * 2);       // 8 MB
  unsigned short* Wc   = (unsigned short*)carve(4ull * 2048 * 2048 * 2);   // 32 MB
  float*          bc   = (float*)carve(4ull * 2048 * 4);                   // 32 KB
  unsigned short* Qp   = (unsigned short*)carve(4194304ull * 2);           // 8 MB
  unsigned short* Kp   = (unsigned short*)carve(16777216ull * 2);          // 32 MB
  unsigned short* Vt   = (unsigned short*)carve(16777216ull * 2);          // 32 MB
  unsigned short* Ao   = (unsigned short*)carve(2048ull * 2048 * 2);       // 8 MB
  float*          Opart= (float*)carve(2ull * 32 * 1024 * 128 * 4);        // 32 MB
  float*          Lpart= (float*)carve(2ull * 32 * 1024 * 4);              // 256 KB

  // output chunk offsets (floats)
  float* out_Kre = out + 4194304;
  float* out_Kim = out + 4194304 + 8388608;
  float* out_Vre = out + 4194304 + 2 * 8388608;
  float* out_Vim = out + 4194304 + 3 * 8388608;

  hipLaunchKernelGGL(ln_kernel, dim3(2048), dim3(256), 0, stream,
                     hre, him, gamma, bre, bim, Aln);
  hipLaunchKernelGGL(wprep_kernel, dim3(8192), dim3(256), 0, stream,
                     qWr, qWi, kWr, kWi, vWr, vWi, oWr, oWi, Wc);
  hipLaunchKernelGGL(bprep_kernel, dim3(32), dim3(256), 0, stream,
                     qbr, qbi, kbr, kbi, vbr, vbi, obr, obi, bc);
  hipLaunchKernelGGL(gemm_qkv_kernel, dim3(48, 16), dim3(256), 0, stream,
                     Aln, Wc, bc, Qp, Kp, out_Kre, out_Kim, out_Vre, out_Vim);
  hipLaunchKernelGGL(pack_kcache_kernel, dim3(384, 32), dim3(256), 0, stream,
                     Kcr, Kci, Kp, out_Kre, out_Kim);
  hipLaunchKernelGGL(pack_vt_fused_kernel, dim3(2048), dim3(256), 0, stream,
                     Vcr, Vci, out_Vre, out_Vim, Vt);
  hipLaunchKernelGGL(attn_kernel, dim3(32, 8, 2), dim3(256), 0, stream,
                     Qp, Kp, Vt, Opart, Lpart);
  hipLaunchKernelGGL(attn_combine_kernel, dim3(2048), dim3(256), 0, stream,
                     Opart, Lpart, Ao);
  hipLaunchKernelGGL(gemm_oproj_kernel, dim3(16, 16), dim3(256), 0, stream,
                     Ao, Wc + 3ull * 2048 * 2048, bc + 3 * 2048, hre, him, out);
}

// Round 3
// 598.592 us; speedup vs baseline: 1.0197x; 1.0051x over previous
//
#include <hip/hip_runtime.h>
#include <hip/hip_bf16.h>
#include <cstdint>
#include <cstddef>

// ---------- types ----------
typedef __bf16 bf16x8 __attribute__((ext_vector_type(8)));
typedef float  f32x4  __attribute__((ext_vector_type(4)));

__device__ __forceinline__ unsigned short f2bf(float f) {
  union { float f; unsigned u; } v; v.f = f;
  unsigned u = v.u;
  u += 0x7FFFu + ((u >> 16) & 1u);   // RNE
  return (unsigned short)(u >> 16);
}

// native cast path: compiler emits v_cvt_pk_bf16_f32 (RNE, same rounding as f2bf)
__device__ __forceinline__ unsigned short f2bf_cvt(float f) {
  __bf16 h = (__bf16)f;
  return __builtin_bit_cast(unsigned short, h);
}

struct alignas(16) US8 { unsigned short u[8]; };

__device__ __forceinline__ void g2lds16(const void* g, void* l) {
  __builtin_amdgcn_global_load_lds(
      (const __attribute__((address_space(1))) unsigned int*)g,
      (__attribute__((address_space(3))) unsigned int*)l, 16, 0, 0);
}

// sizes
#define BB 2
#define SS 1024
#define HID 1024
#define NHH 16
#define HDD 64
#define TT 4096
#define CCH 3072
// Q pre-scale: 1/sqrt(64) * log2(e)  (scores then exponentiated with raw v_exp_f32 = 2^x)
#define QSCALE (0.125f * 1.44269504088896f)

// ---------- LayerNorm (complex) -> Aln bf16 [2048][2048] = [nr | ni] ----------
__global__ __launch_bounds__(256) void ln_kernel(
    const float* __restrict__ hre, const float* __restrict__ him,
    const float* __restrict__ gamma, const float* __restrict__ bre,
    const float* __restrict__ bim, unsigned short* __restrict__ Aln)
{
  int m = blockIdx.x;
  int tid = threadIdx.x;
  const float4 vr = ((const float4*)(hre + (size_t)m * HID))[tid];
  const float4 vi = ((const float4*)(him + (size_t)m * HID))[tid];
  float sr = vr.x + vr.y + vr.z + vr.w;
  float si = vi.x + vi.y + vi.z + vi.w;
  float sq = vr.x*vr.x + vr.y*vr.y + vr.z*vr.z + vr.w*vr.w
           + vi.x*vi.x + vi.y*vi.y + vi.z*vi.z + vi.w*vi.w;
  __shared__ float red[3][4];
  int lane = tid & 63, w = tid >> 6;
  for (int off = 32; off; off >>= 1) {
    sr += __shfl_down(sr, off, 64);
    si += __shfl_down(si, off, 64);
    sq += __shfl_down(sq, off, 64);
  }
  if (lane == 0) { red[0][w] = sr; red[1][w] = si; red[2][w] = sq; }
  __syncthreads();
  sr = red[0][0] + red[0][1] + red[0][2] + red[0][3];
  si = red[1][0] + red[1][1] + red[1][2] + red[1][3];
  sq = red[2][0] + red[2][1] + red[2][2] + red[2][3];
  float mur = sr * (1.f/1024.f), mui = si * (1.f/1024.f);
  float var = sq * (1.f/1024.f) - mur*mur - mui*mui;
  float inv = rsqrtf(var + 1e-5f);
  int k = tid * 4;
  float4 g  = ((const float4*)gamma)[tid];
  float4 br = ((const float4*)bre)[tid];
  float4 bi = ((const float4*)bim)[tid];
  ushort4 nr, ni;
  nr.x = f2bf((vr.x - mur) * inv * g.x + br.x);
  nr.y = f2bf((vr.y - mur) * inv * g.y + br.y);
  nr.z = f2bf((vr.z - mur) * inv * g.z + br.z);
  nr.w = f2bf((vr.w - mur) * inv * g.w + br.w);
  ni.x = f2bf((vi.x - mui) * inv * g.x + bi.x);
  ni.y = f2bf((vi.y - mui) * inv * g.y + bi.y);
  ni.z = f2bf((vi.z - mui) * inv * g.z + bi.z);
  ni.w = f2bf((vi.w - mui) * inv * g.w + bi.w);
  *(ushort4*)&Aln[(size_t)m * 2048 + k]        = nr;
  *(ushort4*)&Aln[(size_t)m * 2048 + 1024 + k] = ni;
}

// ---------- combined weights: Wc[p][n][k] bf16, p in {q,k,v,o}, 2048x2048 each ----------
__global__ __launch_bounds__(256) void wprep_kernel(
    const float* __restrict__ qWr, const float* __restrict__ qWi,
    const float* __restrict__ kWr, const float* __restrict__ kWi,
    const float* __restrict__ vWr, const float* __restrict__ vWi,
    const float* __restrict__ oWr, const float* __restrict__ oWi,
    unsigned short* __restrict__ Wc)
{
  int gid = blockIdx.x * 256 + threadIdx.x;
  int idx = gid * 8;                     // over 4*2048*2048
  int p   = idx >> 22;
  int rem = idx & 0x3FFFFF;
  int n   = rem >> 11;
  int k   = rem & 2047;
  const float* Wr; const float* Wi;
  switch (p) {
    case 0:  Wr = qWr; Wi = qWi; break;
    case 1:  Wr = kWr; Wi = kWi; break;
    case 2:  Wr = vWr; Wi = vWi; break;
    default: Wr = oWr; Wi = oWi; break;
  }
  const float* src; float sgn = 1.f;
  if (n < 1024) {
    if (k < 1024) src = Wr + (size_t)n * 1024 + k;
    else        { src = Wi + (size_t)n * 1024 + (k - 1024); sgn = -1.f; }
  } else {
    if (k < 1024) src = Wi + (size_t)(n - 1024) * 1024 + k;
    else          src = Wr + (size_t)(n - 1024) * 1024 + (k - 1024);
  }
  float4 a = ((const float4*)src)[0];
  float4 b = ((const float4*)src)[1];
  US8 o;
  o.u[0] = f2bf(a.x * sgn); o.u[1] = f2bf(a.y * sgn);
  o.u[2] = f2bf(a.z * sgn); o.u[3] = f2bf(a.w * sgn);
  o.u[4] = f2bf(b.x * sgn); o.u[5] = f2bf(b.y * sgn);
  o.u[6] = f2bf(b.z * sgn); o.u[7] = f2bf(b.w * sgn);
  *(US8*)&Wc[idx] = o;
}

__global__ __launch_bounds__(256) void bprep_kernel(
    const float* __restrict__ qbr, const float* __restrict__ qbi,
    const float* __restrict__ kbr, const float* __restrict__ kbi,
    const float* __restrict__ vbr, const float* __restrict__ vbi,
    const float* __restrict__ obr, const float* __restrict__ obi,
    float* __restrict__ bc)
{
  int idx = blockIdx.x * 256 + threadIdx.x;  // 8192
  int p = idx >> 11, n = idx & 2047;
  const float* br; const float* bi;
  switch (p) {
    case 0:  br = qbr; bi = qbi; break;
    case 1:  br = kbr; bi = kbi; break;
    case 2:  br = vbr; bi = vbi; break;
    default: br = obr; bi = obi; break;
  }
  bc[idx] = (n < 1024) ? br[n] : bi[n - 1024];
}

// ---------- QKV GEMM: A[2048 x 2048] * Wc[6144 x 2048]^T + bias ----------
// Epilogue routes per column section directly into attention-ready buffers.
__global__ __launch_bounds__(256) void gemm_qkv_kernel(
    const unsigned short* __restrict__ A, const unsigned short* __restrict__ Bm,
    const float* __restrict__ bias,
    unsigned short* __restrict__ Qp, unsigned short* __restrict__ Kp,
    float* __restrict__ out_Kre, float* __restrict__ out_Kim,
    float* __restrict__ out_Vre, float* __restrict__ out_Vim)
{
  __shared__ alignas(16) unsigned short As[128][32];
  __shared__ alignas(16) unsigned short Bs[128][32];
  const int K = 2048;
  int bm = blockIdx.y * 128;
  int bn = blockIdx.x * 128;
  int tid = threadIdx.x;
  int lane = tid & 63, w = tid >> 6;
  int wm = (w >> 1) * 64, wn = (w & 1) * 64;
  int l15 = lane & 15, q = lane >> 4;
  int lr = tid >> 2;            // 0..63
  int lc = (tid & 3) * 8;       // 0,8,16,24

  f32x4 acc[4][4] = {};

  for (int k0 = 0; k0 < K; k0 += 32) {
    g2lds16(&A [(size_t)(bm + lr)      * K + k0 + lc], (unsigned short*)As + 8*tid);
    g2lds16(&A [(size_t)(bm + lr + 64) * K + k0 + lc], (unsigned short*)As + 2048 + 8*tid);
    g2lds16(&Bm[(size_t)(bn + lr)      * K + k0 + lc], (unsigned short*)Bs + 8*tid);
    g2lds16(&Bm[(size_t)(bn + lr + 64) * K + k0 + lc], (unsigned short*)Bs + 2048 + 8*tid);
    __syncthreads();
    bf16x8 af[4], bfr[4];
#pragma unroll
    for (int i = 0; i < 4; i++) af[i]  = *(const bf16x8*)&As[wm + i*16 + l15][q*8];
#pragma unroll
    for (int i = 0; i < 4; i++) bfr[i] = *(const bf16x8*)&Bs[wn + i*16 + l15][q*8];
#pragma unroll
    for (int i = 0; i < 4; i++)
#pragma unroll
      for (int j = 0; j < 4; j++)
        acc[i][j] = __builtin_amdgcn_mfma_f32_16x16x32_bf16(af[i], bfr[j], acc[i][j], 0, 0, 0);
    __syncthreads();
  }

  const int sec = bn >> 11;   // 0=Q, 1=K, 2=V (uniform per block; 2048 % 128 == 0)
#pragma unroll
  for (int i = 0; i < 4; i++)
#pragma unroll
    for (int j = 0; j < 4; j++) {
      int n = bn + wn + j*16 + l15;
      float bv = bias[n];
      int col = n & 2047;
      int re = (col < 1024) ? 1 : 0;
      int h = (col & 1023) >> 6, d = col & 63;
      int d2 = re ? d : 64 + d;
#pragma unroll
      for (int r = 0; r < 4; r++) {
        int m = bm + wm + i*16 + q*4 + r;
        float val = acc[i][j][r] + bv;
        int b = m >> 10, s = m & 1023;
        int bh = b*16 + h;
        if (sec == 0) {
          Qp[((size_t)bh*1024 + s)*128 + d2] = f2bf(val * QSCALE);
        } else if (sec == 1) {
          int t = CCH + s;
          Kp[((size_t)bh*4096 + t)*128 + d2] = f2bf(val);
          float* dst = re ? out_Kre : out_Kim;
          dst[(((size_t)b*4096 + t)*16 + h)*64 + d] = val;
        } else {
          int t = CCH + s;
          float* dst = re ? out_Vre : out_Vim;
          dst[(((size_t)b*4096 + t)*16 + h)*64 + d] = val;
        }
      }
    }
}

// ---------- o-proj GEMM with residual + split write to out_re/out_im ----------
__global__ __launch_bounds__(256) void gemm_oproj_kernel(
    const unsigned short* __restrict__ A, const unsigned short* __restrict__ Bm,
    const float* __restrict__ bias, const float* __restrict__ hre,
    const float* __restrict__ him, float* __restrict__ out)
{
  __shared__ alignas(16) unsigned short As[128][32];
  __shared__ alignas(16) unsigned short Bs[128][32];
  int bm = blockIdx.y * 128;
  int bn = blockIdx.x * 128;
  int tid = threadIdx.x;
  int lane = tid & 63, w = tid >> 6;
  int wm = (w >> 1) * 64, wn = (w & 1) * 64;
  int l15 = lane & 15, q = lane >> 4;
  int lr = tid >> 2;
  int lc = (tid & 3) * 8;
  const int K = 2048;

  f32x4 acc[4][4] = {};

  for (int k0 = 0; k0 < K; k0 += 32) {
    g2lds16(&A [(size_t)(bm + lr)      * K + k0 + lc], (unsigned short*)As + 8*tid);
    g2lds16(&A [(size_t)(bm + lr + 64) * K + k0 + lc], (unsigned short*)As + 2048 + 8*tid);
    g2lds16(&Bm[(size_t)(bn + lr)      * K + k0 + lc], (unsigned short*)Bs + 8*tid);
    g2lds16(&Bm[(size_t)(bn + lr + 64) * K + k0 + lc], (unsigned short*)Bs + 2048 + 8*tid);
    __syncthreads();
    bf16x8 af[4], bfr[4];
#pragma unroll
    for (int i = 0; i < 4; i++) af[i]  = *(const bf16x8*)&As[wm + i*16 + l15][q*8];
#pragma unroll
    for (int i = 0; i < 4; i++) bfr[i] = *(const bf16x8*)&Bs[wn + i*16 + l15][q*8];
#pragma unroll
    for (int i = 0; i < 4; i++)
#pragma unroll
      for (int j = 0; j < 4; j++)
        acc[i][j] = __builtin_amdgcn_mfma_f32_16x16x32_bf16(af[i], bfr[j], acc[i][j], 0, 0, 0);
    __syncthreads();
  }

#pragma unroll
  for (int i = 0; i < 4; i++)
#pragma unroll
    for (int j = 0; j < 4; j++) {
      int n = bn + wn + j*16 + l15;
      float bv = bias[n];
#pragma unroll
      for (int r = 0; r < 4; r++) {
        int m = bm + wm + i*16 + q*4 + r;
        float val = acc[i][j][r] + bv;
        if (n < 1024) out[(size_t)m * 1024 + n] = val + hre[(size_t)m * 1024 + n];
        else out[2097152 + (size_t)m * 1024 + (n - 1024)] = val + him[(size_t)m * 1024 + (n - 1024)];
      }
    }
}

// ---------- K cache part: cache -> Kp bf16 [bh][t<3072][128] + out_K f32 ----------
__global__ __launch_bounds__(256) void pack_kcache_kernel(
    const float* __restrict__ c_re, const float* __restrict__ c_im,
    unsigned short* __restrict__ Kp,
    float* __restrict__ out_re, float* __restrict__ out_im)
{
  int bh = blockIdx.y;              // 0..31
  int idx = (blockIdx.x * 256 + threadIdx.x) * 4;  // over 3072*128
  int d2 = idx & 127;
  int t  = idx >> 7;                // 0..3071
  int b = bh >> 4, h = bh & 15;
  int d = d2 & 63;
  bool im = d2 >= 64;
  const float* src = im ? c_im : c_re;
  float4 v = *(const float4*)&src[(((size_t)b * CCH + t) * 16 + h) * 64 + d];
  ushort4 o;
  o.x = f2bf(v.x); o.y = f2bf(v.y); o.z = f2bf(v.z); o.w = f2bf(v.w);
  *(ushort4*)&Kp[((size_t)bh * 4096 + t) * 128 + d2] = o;
  float* dst = im ? out_im : out_re;
  *(float4*)&dst[(((size_t)b * 4096 + t) * 16 + h) * 64 + d] = v;
}

// ---------- fused V: cache -> out_V f32 (+readback of new part) -> Vt bf16 [bh][d2][t] ----------
__global__ __launch_bounds__(256) void pack_vt_fused_kernel(
    const float* __restrict__ Vc_re, const float* __restrict__ Vc_im,
    float* __restrict__ out_Vre, float* __restrict__ out_Vim,
    unsigned short* __restrict__ Vt)
{
  __shared__ float Ts[64][136];
  const int ty = blockIdx.x & 63;   // t-tile
  const int bh = blockIdx.x >> 6;   // 0..31
  const int b = bh >> 4, h = bh & 15;
  const int t0 = ty * 64;
  const int tid = threadIdx.x;
#pragma unroll
  for (int rr = 0; rr < 8; rr++) {
    int j = rr * 256 + tid;
    int t_loc = j >> 5, c = j & 31;
    int d2 = c * 4;
    int t = t0 + t_loc;
    int d = (d2 < 64) ? d2 : d2 - 64;
    float4 v;
    if (t < CCH) {
      const float* src = (d2 < 64) ? Vc_re : Vc_im;
      v = *(const float4*)&src[(((size_t)b * CCH + t) * 16 + h) * 64 + d];
      float* dst = (d2 < 64) ? out_Vre : out_Vim;
      *(float4*)&dst[(((size_t)b * 4096 + t) * 16 + h) * 64 + d] = v;
    } else {
      const float* src = (d2 < 64) ? out_Vre : out_Vim;   // written by gemm_qkv
      v = *(const float4*)&src[(((size_t)b * 4096 + t) * 16 + h) * 64 + d];
    }
    *(float4*)&Ts[t_loc][d2] = v;
  }
  __syncthreads();
  const int d2 = tid >> 1, half = tid & 1;
  unsigned short tmp[32];
#pragma unroll
  for (int i = 0; i < 32; i++) tmp[i] = f2bf(Ts[half*32 + i][d2]);
  size_t dst = (size_t)bh * 128 * 4096 + (size_t)d2 * 4096 + t0 + half*32;
#pragma unroll
  for (int kq = 0; kq < 4; kq++)
    *(US8*)&Vt[dst + kq*8] = *(US8*)&tmp[kq*8];
}

// ---------- flash attention: 128 q-rows/block, T=32 t-tiles, 3-way t-split ----------
// Qp [bh][s][128] (pre-scaled QSCALE), Kp [bh][t][128], Vt [bh][d2][t]
// LDS = Ks 16K + Vs 16K + Ps 10K = 42 KB -> 3 blocks/CU (12 waves/CU).
// Ps rows padded to 40 ushorts (80 B, 16B-aligned): write banks = 16q+20r+8nc+(l15>>1)
// -> worst 2-way (free); no XOR swizzle needed on Ps.
__global__ __launch_bounds__(256) void attn_kernel(
    const unsigned short* __restrict__ Qp, const unsigned short* __restrict__ Kp,
    const unsigned short* __restrict__ Vt, float* __restrict__ Opart,
    float* __restrict__ Lpart)
{
  const int bh   = blockIdx.x;   // 0..31
  const int sblk = blockIdx.y;   // 0..7
  const int tpar = blockIdx.z;   // 0..2
  const int s0 = sblk * 128;
  const int tid = threadIdx.x;
  const int lane = tid & 63, w = tid >> 6;
  const int l15 = lane & 15, q = lane >> 4;

  __shared__ alignas(16) unsigned short Ks[2][32][128];  // 16 KB
  __shared__ alignas(16) unsigned short Vs[2][128][32];  // 16 KB
  __shared__ alignas(16) unsigned short Ps[4][32][40];   // 10 KB (padded rows)

  // persistent Q fragments: 2 m-frags x 4 k-chunks
  bf16x8 qf[2][4];
#pragma unroll
  for (int mi = 0; mi < 2; mi++) {
    const size_t qb = ((size_t)bh * 1024 + s0 + w*32 + mi*16 + l15) * 128;
#pragma unroll
    for (int kc = 0; kc < 4; kc++)
      qf[mi][kc] = *(const bf16x8*)&Qp[qb + kc*32 + q*8];
  }

  f32x4 oacc[2][8] = {};
  float lsum[2][4] = {};

  const size_t kpb = (size_t)bh * 4096 * 128;
  const size_t vtb = (size_t)bh * 128 * 4096;
  const int n_tiles = 4*sblk + 100;   // tiles of 32 t
  const int n_safe  = n_tiles - 4;    // last 4 tiles need causal masking

  // staging: 512 16B-chunks per K tile and per V tile; each wave does 2+2
  // LDS dest linear in lane (DMA requirement); swizzle applied on global src.
  auto issue = [&](int buf, int t0) {
#pragma unroll
    for (int kk = 0; kk < 2; kk++) {
      int j = (w*2 + kk)*64 + lane;          // chunk index 0..511
      int r = j >> 4, p = j & 15, c = p ^ (r & 7);
      g2lds16(&Kp[kpb + (size_t)(t0 + r) * 128 + c*8],
              (unsigned short*)&Ks[buf][0][0] + (size_t)j * 8);
    }
#pragma unroll
    for (int kk = 0; kk < 2; kk++) {
      int j = (w*2 + kk)*64 + lane;
      int r = j >> 2, p = j & 3, c = p ^ (r & 3);
      g2lds16(&Vt[vtb + (size_t)r * 4096 + t0 + c*8],
              (unsigned short*)&Vs[buf][0][0] + (size_t)j * 8);
    }
  };

  int buf = 0;
  issue(0, tpar * 32);

  for (int it = tpar; it < n_tiles; it += 3) {
    __syncthreads();                       // drains loads for `buf`
    if (it + 3 < n_tiles) issue(buf ^ 1, (it + 3) * 32);   // overlap with compute

    // QK^T  (32 t-cols per tile: nc = 0,1)
    f32x4 sacc[2][2] = {};
    __builtin_amdgcn_s_setprio(1);
#pragma unroll
    for (int kc = 0; kc < 4; kc++) {
      bf16x8 kf[2];
#pragma unroll
      for (int nc = 0; nc < 2; nc++)
        kf[nc] = *(const bf16x8*)&Ks[buf][nc*16 + l15][((kc*4 + q) ^ (l15 & 7)) * 8];
#pragma unroll
      for (int mi = 0; mi < 2; mi++)
#pragma unroll
        for (int nc = 0; nc < 2; nc++)
          sacc[mi][nc] = __builtin_amdgcn_mfma_f32_16x16x32_bf16(qf[mi][kc], kf[nc], sacc[mi][nc], 0, 0, 0);
    }
    __builtin_amdgcn_s_setprio(0);

    // exp2 + P store (pad-spread, conflict-free), mask only last 4 tiles
    const bool safe = (it < n_safe);
    const int t0 = it << 5;
#pragma unroll
    for (int mi = 0; mi < 2; mi++)
#pragma unroll
      for (int r = 0; r < 4; r++) {
        const int rr = mi*16 + q*4 + r;
        const int rel = s0 + w*32 + rr + CCH - t0;
        float ls = 0.f;
#pragma unroll
        for (int nc = 0; nc < 2; nc++) {
          float p;
          asm("v_exp_f32 %0, %1" : "=v"(p) : "v"(sacc[mi][nc][r]));   // 2^x; log2e folded into Qp
          if (!safe && (nc*16 + l15 > rel)) p = 0.f;
          ls += p;
          Ps[w][rr][nc*16 + l15] = f2bf_cvt(p);
        }
        lsum[mi][r] += ls;
      }

    // PV (single 32-k chunk)
    bf16x8 pf[2];
#pragma unroll
    for (int mi = 0; mi < 2; mi++)
      pf[mi] = *(const bf16x8*)&Ps[w][mi*16 + l15][q*8];
    __builtin_amdgcn_s_setprio(1);
#pragma unroll
    for (int dc = 0; dc < 8; dc++) {
      int d2 = dc*16 + l15;
      bf16x8 vfr = *(const bf16x8*)&Vs[buf][d2][(q ^ (d2 & 3)) * 8];
#pragma unroll
      for (int mi = 0; mi < 2; mi++)
        oacc[mi][dc] = __builtin_amdgcn_mfma_f32_16x16x32_bf16(pf[mi], vfr, oacc[mi][dc], 0, 0, 0);
    }
    __builtin_amdgcn_s_setprio(0);
    buf ^= 1;
  }

  // write partials
  const size_t pb = ((size_t)tpar * 32 + bh) * 1024 + s0 + w*32;
#pragma unroll
  for (int mi = 0; mi < 2; mi++)
#pragma unroll
    for (int r = 0; r < 4; r++) {
      float l = lsum[mi][r];
      l += __shfl_xor(l, 1, 64);
      l += __shfl_xor(l, 2, 64);
      l += __shfl_xor(l, 4, 64);
      l += __shfl_xor(l, 8, 64);
      if (l15 == 0) Lpart[pb + mi*16 + q*4 + r] = l;
    }
#pragma unroll
  for (int mi = 0; mi < 2; mi++)
#pragma unroll
    for (int dc = 0; dc < 8; dc++)
#pragma unroll
      for (int r = 0; r < 4; r++)
        Opart[(pb + mi*16 + q*4 + r) * 128 + dc*16 + l15] = oacc[mi][dc][r];
}

// ---------- combine 3 partials -> Ao bf16 [m][2048] ----------
__global__ __launch_bounds__(256) void attn_combine_kernel(
    const float* __restrict__ Opart, const float* __restrict__ Lpart,
    unsigned short* __restrict__ Ao)
{
  const size_t TS = 4194304ull;   // tpar stride in floats (32*1024*128)
  int gid = blockIdx.x * 256 + threadIdx.x;
  int idx = gid * 8;              // over 2048*2048
  int m = idx >> 11, n0 = idx & 2047;
  int b = m >> 10, s = m & 1023;
  int h, d2_0;
  if (n0 < 1024) { h = n0 >> 6; d2_0 = n0 & 63; }
  else { h = (n0 - 1024) >> 6; d2_0 = 64 + ((n0 - 1024) & 63); }
  int bh = b*16 + h;
  size_t ob = ((size_t)bh * 1024 + s) * 128 + d2_0;
  float l0 = Lpart[(size_t)bh * 1024 + s];
  float l1 = Lpart[32768 + (size_t)bh * 1024 + s];
  float l2 = Lpart[65536 + (size_t)bh * 1024 + s];
  float inv = 1.f / (l0 + l1 + l2);
  float4 x0 = *(const float4*)&Opart[ob];
  float4 x1 = *(const float4*)&Opart[ob + 4];
  float4 y0 = *(const float4*)&Opart[ob + TS];
  float4 y1 = *(const float4*)&Opart[ob + TS + 4];
  float4 z0 = *(const float4*)&Opart[ob + 2*TS];
  float4 z1 = *(const float4*)&Opart[ob + 2*TS + 4];
  US8 o;
  o.u[0] = f2bf((x0.x + y0.x + z0.x) * inv); o.u[1] = f2bf((x0.y + y0.y + z0.y) * inv);
  o.u[2] = f2bf((x0.z + y0.z + z0.z) * inv); o.u[3] = f2bf((x0.w + y0.w + z0.w) * inv);
  o.u[4] = f2bf((x1.x + y1.x + z1.x) * inv); o.u[5] = f2bf((x1.y + y1.y + z1.y) * inv);
  o.u[6] = f2bf((x1.z + y1.z + z1.z) * inv); o.u[7] = f2bf((x1.w + y1.w + z1.w) * inv);
  *(US8*)&Ao[idx] = o;
}

// ---------- launch ----------
extern "C" void kernel_launch(void* const* d_in, const int* in_sizes, int n_in,
                              void* d_out, int out_size, void* d_ws, size_t ws_size,
                              hipStream_t stream)
{
  (void)in_sizes; (void)n_in; (void)out_size; (void)ws_size;
  const float* hre = (const float*)d_in[0];
  const float* him = (const float*)d_in[1];
  const float* Kcr = (const float*)d_in[2];
  const float* Kci = (const float*)d_in[3];
  const float* Vcr = (const float*)d_in[4];
  const float* Vci = (const float*)d_in[5];
  const float* gamma = (const float*)d_in[6];
  const float* bre = (const float*)d_in[7];
  const float* bim = (const float*)d_in[8];
  const float* qWr = (const float*)d_in[9];
  const float* qWi = (const float*)d_in[10];
  const float* qbr = (const float*)d_in[11];
  const float* qbi = (const float*)d_in[12];
  const float* kWr = (const float*)d_in[13];
  const float* kWi = (const float*)d_in[14];
  const float* kbr = (const float*)d_in[15];
  const float* kbi = (const float*)d_in[16];
  const float* vWr = (const float*)d_in[17];
  const float* vWi = (const float*)d_in[18];
  const float* vbr = (const float*)d_in[19];
  const float* vbi = (const float*)d_in[20];
  const float* oWr = (const float*)d_in[21];
  const float* oWi = (const float*)d_in[22];
  const float* obr = (const float*)d_in[23];
  const float* obi = (const float*)d_in[24];
  float* out = (float*)d_out;

  char* ws = (char*)d_ws;
  size_t off = 0;
  auto carve = [&](size_t bytes) {
    char* p = ws + off;
    off += (bytes + 255) & ~(size_t)255;
    return p;
  };
  unsigned short* Aln  = (unsigned short*)carve(2048ull * 2048 * 2);       // 8 MB (dead after gemm_qkv; reused as Ao)
  unsigned short* Wc   = (unsigned short*)carve(4ull * 2048 * 2048 * 2);   // 32 MB
  float*          bc   = (float*)carve(4ull * 2048 * 4);                   // 32 KB
  unsigned short* Qp   = (unsigned short*)carve(4194304ull * 2);           // 8 MB
  unsigned short* Kp   = (unsigned short*)carve(16777216ull * 2);          // 32 MB
  unsigned short* Vt   = (unsigned short*)carve(16777216ull * 2);          // 32 MB
  float*          Opart= (float*)carve(3ull * 32 * 1024 * 128 * 4);        // 48 MB
  float*          Lpart= (float*)carve(3ull * 32 * 1024 * 4);              // 384 KB

  unsigned short* Ao = Aln;   // alias: Aln dead after gemm_qkv, combine runs later

  // output chunk offsets (floats)
  float* out_Kre = out + 4194304;
  float* out_Kim = out + 4194304 + 8388608;
  float* out_Vre = out + 4194304 + 2 * 8388608;
  float* out_Vim = out + 4194304 + 3 * 8388608;

  hipLaunchKernelGGL(ln_kernel, dim3(2048), dim3(256), 0, stream,
                     hre, him, gamma, bre, bim, Aln);
  hipLaunchKernelGGL(wprep_kernel, dim3(8192), dim3(256), 0, stream,
                     qWr, qWi, kWr, kWi, vWr, vWi, oWr, oWi, Wc);
  hipLaunchKernelGGL(bprep_kernel, dim3(32), dim3(256), 0, stream,
                     qbr, qbi, kbr, kbi, vbr, vbi, obr, obi, bc);
  hipLaunchKernelGGL(gemm_qkv_kernel, dim3(48, 16), dim3(256), 0, stream,
                     Aln, Wc, bc, Qp, Kp, out_Kre, out_Kim, out_Vre, out_Vim);
  hipLaunchKernelGGL(pack_kcache_kernel, dim3(384, 32), dim3(256), 0, stream,
                     Kcr, Kci, Kp, out_Kre, out_Kim);
  hipLaunchKernelGGL(pack_vt_fused_kernel, dim3(2048), dim3(256), 0, stream,
                     Vcr, Vci, out_Vre, out_Vim, Vt);
  hipLaunchKernelGGL(attn_kernel, dim3(32, 8, 3), dim3(256), 0, stream,
                     Qp, Kp, Vt, Opart, Lpart);
  hipLaunchKernelGGL(attn_combine_kernel, dim3(2048), dim3(256), 0, stream,
                     Opart, Lpart, Ao);
  hipLaunchKernelGGL(gemm_oproj_kernel, dim3(16, 16), dim3(256), 0, stream,
                     Ao, Wc + 3ull * 2048 * 2048, bc + 3 * 2048, hre, him, out);
}

// Round 4
// 572.060 us; speedup vs baseline: 1.0670x; 1.0464x over previous
//
#include <hip/hip_runtime.h>
#include <hip/hip_bf16.h>
#include <cstdint>
#include <cstddef>

// ---------- types ----------
typedef __bf16 bf16x8 __attribute__((ext_vector_type(8)));
typedef float  f32x4  __attribute__((ext_vector_type(4)));

__device__ __forceinline__ unsigned short f2bf(float f) {
  union { float f; unsigned u; } v; v.f = f;
  unsigned u = v.u;
  u += 0x7FFFu + ((u >> 16) & 1u);   // RNE
  return (unsigned short)(u >> 16);
}

// native cast path: compiler emits v_cvt_pk_bf16_f32 (RNE, same rounding as f2bf)
__device__ __forceinline__ unsigned short f2bf_cvt(float f) {
  __bf16 h = (__bf16)f;
  return __builtin_bit_cast(unsigned short, h);
}

struct alignas(16) US8 { unsigned short u[8]; };

__device__ __forceinline__ void g2lds16(const void* g, void* l) {
  __builtin_amdgcn_global_load_lds(
      (const __attribute__((address_space(1))) unsigned int*)g,
      (__attribute__((address_space(3))) unsigned int*)l, 16, 0, 0);
}

// sizes
#define BB 2
#define SS 1024
#define HID 1024
#define NHH 16
#define HDD 64
#define TT 4096
#define CCH 3072
// Q pre-scale: 1/sqrt(64) * log2(e)  (scores then exponentiated with raw v_exp_f32 = 2^x)
#define QSCALE (0.125f * 1.44269504088896f)

// ---------- LayerNorm (complex) -> Aln bf16 [2048][2048] = [nr | ni] ----------
__global__ __launch_bounds__(256) void ln_kernel(
    const float* __restrict__ hre, const float* __restrict__ him,
    const float* __restrict__ gamma, const float* __restrict__ bre,
    const float* __restrict__ bim, unsigned short* __restrict__ Aln)
{
  int m = blockIdx.x;
  int tid = threadIdx.x;
  const float4 vr = ((const float4*)(hre + (size_t)m * HID))[tid];
  const float4 vi = ((const float4*)(him + (size_t)m * HID))[tid];
  float sr = vr.x + vr.y + vr.z + vr.w;
  float si = vi.x + vi.y + vi.z + vi.w;
  float sq = vr.x*vr.x + vr.y*vr.y + vr.z*vr.z + vr.w*vr.w
           + vi.x*vi.x + vi.y*vi.y + vi.z*vi.z + vi.w*vi.w;
  __shared__ float red[3][4];
  int lane = tid & 63, w = tid >> 6;
  for (int off = 32; off; off >>= 1) {
    sr += __shfl_down(sr, off, 64);
    si += __shfl_down(si, off, 64);
    sq += __shfl_down(sq, off, 64);
  }
  if (lane == 0) { red[0][w] = sr; red[1][w] = si; red[2][w] = sq; }
  __syncthreads();
  sr = red[0][0] + red[0][1] + red[0][2] + red[0][3];
  si = red[1][0] + red[1][1] + red[1][2] + red[1][3];
  sq = red[2][0] + red[2][1] + red[2][2] + red[2][3];
  float mur = sr * (1.f/1024.f), mui = si * (1.f/1024.f);
  float var = sq * (1.f/1024.f) - mur*mur - mui*mui;
  float inv = rsqrtf(var + 1e-5f);
  int k = tid * 4;
  float4 g  = ((const float4*)gamma)[tid];
  float4 br = ((const float4*)bre)[tid];
  float4 bi = ((const float4*)bim)[tid];
  ushort4 nr, ni;
  nr.x = f2bf((vr.x - mur) * inv * g.x + br.x);
  nr.y = f2bf((vr.y - mur) * inv * g.y + br.y);
  nr.z = f2bf((vr.z - mur) * inv * g.z + br.z);
  nr.w = f2bf((vr.w - mur) * inv * g.w + br.w);
  ni.x = f2bf((vi.x - mui) * inv * g.x + bi.x);
  ni.y = f2bf((vi.y - mui) * inv * g.y + bi.y);
  ni.z = f2bf((vi.z - mui) * inv * g.z + bi.z);
  ni.w = f2bf((vi.w - mui) * inv * g.w + bi.w);
  *(ushort4*)&Aln[(size_t)m * 2048 + k]        = nr;
  *(ushort4*)&Aln[(size_t)m * 2048 + 1024 + k] = ni;
}

// ---------- combined weights: Wc[p][n][k] bf16, p in {q,k,v,o}, 2048x2048 each ----------
__global__ __launch_bounds__(256) void wprep_kernel(
    const float* __restrict__ qWr, const float* __restrict__ qWi,
    const float* __restrict__ kWr, const float* __restrict__ kWi,
    const float* __restrict__ vWr, const float* __restrict__ vWi,
    const float* __restrict__ oWr, const float* __restrict__ oWi,
    unsigned short* __restrict__ Wc)
{
  int gid = blockIdx.x * 256 + threadIdx.x;
  int idx = gid * 8;                     // over 4*2048*2048
  int p   = idx >> 22;
  int rem = idx & 0x3FFFFF;
  int n   = rem >> 11;
  int k   = rem & 2047;
  const float* Wr; const float* Wi;
  switch (p) {
    case 0:  Wr = qWr; Wi = qWi; break;
    case 1:  Wr = kWr; Wi = kWi; break;
    case 2:  Wr = vWr; Wi = vWi; break;
    default: Wr = oWr; Wi = oWi; break;
  }
  const float* src; float sgn = 1.f;
  if (n < 1024) {
    if (k < 1024) src = Wr + (size_t)n * 1024 + k;
    else        { src = Wi + (size_t)n * 1024 + (k - 1024); sgn = -1.f; }
  } else {
    if (k < 1024) src = Wi + (size_t)(n - 1024) * 1024 + k;
    else          src = Wr + (size_t)(n - 1024) * 1024 + (k - 1024);
  }
  float4 a = ((const float4*)src)[0];
  float4 b = ((const float4*)src)[1];
  US8 o;
  o.u[0] = f2bf(a.x * sgn); o.u[1] = f2bf(a.y * sgn);
  o.u[2] = f2bf(a.z * sgn); o.u[3] = f2bf(a.w * sgn);
  o.u[4] = f2bf(b.x * sgn); o.u[5] = f2bf(b.y * sgn);
  o.u[6] = f2bf(b.z * sgn); o.u[7] = f2bf(b.w * sgn);
  *(US8*)&Wc[idx] = o;
}

__global__ __launch_bounds__(256) void bprep_kernel(
    const float* __restrict__ qbr, const float* __restrict__ qbi,
    const float* __restrict__ kbr, const float* __restrict__ kbi,
    const float* __restrict__ vbr, const float* __restrict__ vbi,
    const float* __restrict__ obr, const float* __restrict__ obi,
    float* __restrict__ bc)
{
  int idx = blockIdx.x * 256 + threadIdx.x;  // 8192
  int p = idx >> 11, n = idx & 2047;
  const float* br; const float* bi;
  switch (p) {
    case 0:  br = qbr; bi = qbi; break;
    case 1:  br = kbr; bi = kbi; break;
    case 2:  br = vbr; bi = vbi; break;
    default: br = obr; bi = obi; break;
  }
  bc[idx] = (n < 1024) ? br[n] : bi[n - 1024];
}

// ---------- QKV GEMM: A[2048 x 2048] * Wc[6144 x 2048]^T + bias ----------
// 3-buffer global_load_lds pipeline with counted vmcnt (never drains to 0 in
// steady state): per iter {vmcnt(4); s_barrier; stage t+2; ds_read/MFMA t}.
// Chunk-XOR c = p ^ ((row>>1)&3) applied on global source + read side: LDS dest
// stays DMA-linear, ds_read_b128 phases hit all 32 banks (was 4-way conflict).
__global__ __launch_bounds__(256) void gemm_qkv_kernel(
    const unsigned short* __restrict__ A, const unsigned short* __restrict__ Bm,
    const float* __restrict__ bias,
    unsigned short* __restrict__ Qp, unsigned short* __restrict__ Kp,
    float* __restrict__ out_Kre, float* __restrict__ out_Kim,
    float* __restrict__ out_Vre, float* __restrict__ out_Vim)
{
  __shared__ alignas(16) unsigned short As[3][128][32];   // 24 KB
  __shared__ alignas(16) unsigned short Bs[3][128][32];   // 24 KB
  const int K = 2048;
  const int NT = K / 32;   // 64
  int bm = blockIdx.y * 128;
  int bn = blockIdx.x * 128;
  int tid = threadIdx.x;
  int lane = tid & 63, w = tid >> 6;
  int wm = (w >> 1) * 64, wn = (w & 1) * 64;
  int l15 = lane & 15, q = lane >> 4;
  int lr = tid >> 2;                         // staged row 0..63
  int lcs = ((tid & 3) ^ ((tid >> 3) & 3)) * 8;  // source chunk, XOR-swizzled

  const unsigned short* A0 = A  + (size_t)(bm + lr)      * K + lcs;
  const unsigned short* A1 = A  + (size_t)(bm + lr + 64) * K + lcs;
  const unsigned short* B0 = Bm + (size_t)(bn + lr)      * K + lcs;
  const unsigned short* B1 = Bm + (size_t)(bn + lr + 64) * K + lcs;
  const int rsw = ((l15 >> 1) & 3);          // read-side XOR (row>>1)&3 == (l15>>1)&3

  f32x4 acc[4][4] = {};

  auto stage = [&](int b, int t) {
    int k0 = t * 32;
    g2lds16(A0 + k0, (unsigned short*)As[b] + 8*tid);
    g2lds16(A1 + k0, (unsigned short*)As[b] + 2048 + 8*tid);
    g2lds16(B0 + k0, (unsigned short*)Bs[b] + 8*tid);
    g2lds16(B1 + k0, (unsigned short*)Bs[b] + 2048 + 8*tid);
  };

  stage(0, 0);
  stage(1, 1);

  int bc_ = 0, bp_ = 2;
  for (int t = 0; t < NT; ++t) {
    if (t + 1 < NT) asm volatile("s_waitcnt vmcnt(4)" ::: "memory");
    else            asm volatile("s_waitcnt vmcnt(0)" ::: "memory");
    __builtin_amdgcn_s_barrier();
    __builtin_amdgcn_sched_barrier(0);
    if (t + 2 < NT) stage(bp_, t + 2);

    bf16x8 af[4], bfr[4];
#pragma unroll
    for (int i = 0; i < 4; i++) af[i]  = *(const bf16x8*)&As[bc_][wm + i*16 + l15][(q ^ rsw) * 8];
#pragma unroll
    for (int i = 0; i < 4; i++) bfr[i] = *(const bf16x8*)&Bs[bc_][wn + i*16 + l15][(q ^ rsw) * 8];
#pragma unroll
    for (int i = 0; i < 4; i++)
#pragma unroll
      for (int j = 0; j < 4; j++)
        acc[i][j] = __builtin_amdgcn_mfma_f32_16x16x32_bf16(af[i], bfr[j], acc[i][j], 0, 0, 0);

    bc_ = (bc_ == 2) ? 0 : bc_ + 1;
    bp_ = (bp_ == 2) ? 0 : bp_ + 1;
  }

  const int sec = bn >> 11;   // 0=Q, 1=K, 2=V (uniform per block; 2048 % 128 == 0)
#pragma unroll
  for (int i = 0; i < 4; i++)
#pragma unroll
    for (int j = 0; j < 4; j++) {
      int n = bn + wn + j*16 + l15;
      float bv = bias[n];
      int col = n & 2047;
      int re = (col < 1024) ? 1 : 0;
      int h = (col & 1023) >> 6, d = col & 63;
      int d2 = re ? d : 64 + d;
#pragma unroll
      for (int r = 0; r < 4; r++) {
        int m = bm + wm + i*16 + q*4 + r;
        float val = acc[i][j][r] + bv;
        int b = m >> 10, s = m & 1023;
        int bh = b*16 + h;
        if (sec == 0) {
          Qp[((size_t)bh*1024 + s)*128 + d2] = f2bf(val * QSCALE);
        } else if (sec == 1) {
          int t = CCH + s;
          Kp[((size_t)bh*4096 + t)*128 + d2] = f2bf(val);
          float* dst = re ? out_Kre : out_Kim;
          dst[(((size_t)b*4096 + t)*16 + h)*64 + d] = val;
        } else {
          int t = CCH + s;
          float* dst = re ? out_Vre : out_Vim;
          dst[(((size_t)b*4096 + t)*16 + h)*64 + d] = val;
        }
      }
    }
}

// ---------- o-proj GEMM with residual + split write (same pipelined structure) ----------
__global__ __launch_bounds__(256) void gemm_oproj_kernel(
    const unsigned short* __restrict__ A, const unsigned short* __restrict__ Bm,
    const float* __restrict__ bias, const float* __restrict__ hre,
    const float* __restrict__ him, float* __restrict__ out)
{
  __shared__ alignas(16) unsigned short As[3][128][32];
  __shared__ alignas(16) unsigned short Bs[3][128][32];
  const int K = 2048;
  const int NT = K / 32;
  int bm = blockIdx.y * 128;
  int bn = blockIdx.x * 128;
  int tid = threadIdx.x;
  int lane = tid & 63, w = tid >> 6;
  int wm = (w >> 1) * 64, wn = (w & 1) * 64;
  int l15 = lane & 15, q = lane >> 4;
  int lr = tid >> 2;
  int lcs = ((tid & 3) ^ ((tid >> 3) & 3)) * 8;

  const unsigned short* A0 = A  + (size_t)(bm + lr)      * K + lcs;
  const unsigned short* A1 = A  + (size_t)(bm + lr + 64) * K + lcs;
  const unsigned short* B0 = Bm + (size_t)(bn + lr)      * K + lcs;
  const unsigned short* B1 = Bm + (size_t)(bn + lr + 64) * K + lcs;
  const int rsw = ((l15 >> 1) & 3);

  f32x4 acc[4][4] = {};

  auto stage = [&](int b, int t) {
    int k0 = t * 32;
    g2lds16(A0 + k0, (unsigned short*)As[b] + 8*tid);
    g2lds16(A1 + k0, (unsigned short*)As[b] + 2048 + 8*tid);
    g2lds16(B0 + k0, (unsigned short*)Bs[b] + 8*tid);
    g2lds16(B1 + k0, (unsigned short*)Bs[b] + 2048 + 8*tid);
  };

  stage(0, 0);
  stage(1, 1);

  int bc_ = 0, bp_ = 2;
  for (int t = 0; t < NT; ++t) {
    if (t + 1 < NT) asm volatile("s_waitcnt vmcnt(4)" ::: "memory");
    else            asm volatile("s_waitcnt vmcnt(0)" ::: "memory");
    __builtin_amdgcn_s_barrier();
    __builtin_amdgcn_sched_barrier(0);
    if (t + 2 < NT) stage(bp_, t + 2);

    bf16x8 af[4], bfr[4];
#pragma unroll
    for (int i = 0; i < 4; i++) af[i]  = *(const bf16x8*)&As[bc_][wm + i*16 + l15][(q ^ rsw) * 8];
#pragma unroll
    for (int i = 0; i < 4; i++) bfr[i] = *(const bf16x8*)&Bs[bc_][wn + i*16 + l15][(q ^ rsw) * 8];
#pragma unroll
    for (int i = 0; i < 4; i++)
#pragma unroll
      for (int j = 0; j < 4; j++)
        acc[i][j] = __builtin_amdgcn_mfma_f32_16x16x32_bf16(af[i], bfr[j], acc[i][j], 0, 0, 0);

    bc_ = (bc_ == 2) ? 0 : bc_ + 1;
    bp_ = (bp_ == 2) ? 0 : bp_ + 1;
  }

#pragma unroll
  for (int i = 0; i < 4; i++)
#pragma unroll
    for (int j = 0; j < 4; j++) {
      int n = bn + wn + j*16 + l15;
      float bv = bias[n];
#pragma unroll
      for (int r = 0; r < 4; r++) {
        int m = bm + wm + i*16 + q*4 + r;
        float val = acc[i][j][r] + bv;
        if (n < 1024) out[(size_t)m * 1024 + n] = val + hre[(size_t)m * 1024 + n];
        else out[2097152 + (size_t)m * 1024 + (n - 1024)] = val + him[(size_t)m * 1024 + (n - 1024)];
      }
    }
}

// ---------- K cache part: cache -> Kp bf16 [bh][t<3072][128] + out_K f32 ----------
__global__ __launch_bounds__(256) void pack_kcache_kernel(
    const float* __restrict__ c_re, const float* __restrict__ c_im,
    unsigned short* __restrict__ Kp,
    float* __restrict__ out_re, float* __restrict__ out_im)
{
  int bh = blockIdx.y;              // 0..31
  int idx = (blockIdx.x * 256 + threadIdx.x) * 4;  // over 3072*128
  int d2 = idx & 127;
  int t  = idx >> 7;                // 0..3071
  int b = bh >> 4, h = bh & 15;
  int d = d2 & 63;
  bool im = d2 >= 64;
  const float* src = im ? c_im : c_re;
  float4 v = *(const float4*)&src[(((size_t)b * CCH + t) * 16 + h) * 64 + d];
  ushort4 o;
  o.x = f2bf(v.x); o.y = f2bf(v.y); o.z = f2bf(v.z); o.w = f2bf(v.w);
  *(ushort4*)&Kp[((size_t)bh * 4096 + t) * 128 + d2] = o;
  float* dst = im ? out_im : out_re;
  *(float4*)&dst[(((size_t)b * 4096 + t) * 16 + h) * 64 + d] = v;
}

// ---------- fused V: cache -> out_V f32 (+readback of new part) -> Vt bf16 [bh][d2][t] ----------
__global__ __launch_bounds__(256) void pack_vt_fused_kernel(
    const float* __restrict__ Vc_re, const float* __restrict__ Vc_im,
    float* __restrict__ out_Vre, float* __restrict__ out_Vim,
    unsigned short* __restrict__ Vt)
{
  __shared__ float Ts[64][136];
  const int ty = blockIdx.x & 63;   // t-tile
  const int bh = blockIdx.x >> 6;   // 0..31
  const int b = bh >> 4, h = bh & 15;
  const int t0 = ty * 64;
  const int tid = threadIdx.x;
#pragma unroll
  for (int rr = 0; rr < 8; rr++) {
    int j = rr * 256 + tid;
    int t_loc = j >> 5, c = j & 31;
    int d2 = c * 4;
    int t = t0 + t_loc;
    int d = (d2 < 64) ? d2 : d2 - 64;
    float4 v;
    if (t < CCH) {
      const float* src = (d2 < 64) ? Vc_re : Vc_im;
      v = *(const float4*)&src[(((size_t)b * CCH + t) * 16 + h) * 64 + d];
      float* dst = (d2 < 64) ? out_Vre : out_Vim;
      *(float4*)&dst[(((size_t)b * 4096 + t) * 16 + h) * 64 + d] = v;
    } else {
      const float* src = (d2 < 64) ? out_Vre : out_Vim;   // written by gemm_qkv
      v = *(const float4*)&src[(((size_t)b * 4096 + t) * 16 + h) * 64 + d];
    }
    *(float4*)&Ts[t_loc][d2] = v;
  }
  __syncthreads();
  const int d2 = tid >> 1, half = tid & 1;
  unsigned short tmp[32];
#pragma unroll
  for (int i = 0; i < 32; i++) tmp[i] = f2bf(Ts[half*32 + i][d2]);
  size_t dst = (size_t)bh * 128 * 4096 + (size_t)d2 * 4096 + t0 + half*32;
#pragma unroll
  for (int kq = 0; kq < 4; kq++)
    *(US8*)&Vt[dst + kq*8] = *(US8*)&tmp[kq*8];
}

// ---------- flash attention: 128 q-rows/block, T=32 t-tiles, 3-way t-split ----------
// Qp [bh][s][128] (pre-scaled QSCALE), Kp [bh][t][128], Vt [bh][d2][t]
// LDS = Ks 16K + Vs 16K + Ps 10K = 42 KB -> 3 blocks/CU (12 waves/CU).
// Vs chunk swizzle c = p ^ ((r>>1)&3): conflict-free under 16-lane b128 phasing.
__global__ __launch_bounds__(256) void attn_kernel(
    const unsigned short* __restrict__ Qp, const unsigned short* __restrict__ Kp,
    const unsigned short* __restrict__ Vt, float* __restrict__ Opart,
    float* __restrict__ Lpart)
{
  const int bh   = blockIdx.x;   // 0..31
  const int sblk = blockIdx.y;   // 0..7
  const int tpar = blockIdx.z;   // 0..2
  const int s0 = sblk * 128;
  const int tid = threadIdx.x;
  const int lane = tid & 63, w = tid >> 6;
  const int l15 = lane & 15, q = lane >> 4;

  __shared__ alignas(16) unsigned short Ks[2][32][128];  // 16 KB
  __shared__ alignas(16) unsigned short Vs[2][128][32];  // 16 KB
  __shared__ alignas(16) unsigned short Ps[4][32][40];   // 10 KB (padded rows)

  // persistent Q fragments: 2 m-frags x 4 k-chunks
  bf16x8 qf[2][4];
#pragma unroll
  for (int mi = 0; mi < 2; mi++) {
    const size_t qb = ((size_t)bh * 1024 + s0 + w*32 + mi*16 + l15) * 128;
#pragma unroll
    for (int kc = 0; kc < 4; kc++)
      qf[mi][kc] = *(const bf16x8*)&Qp[qb + kc*32 + q*8];
  }

  f32x4 oacc[2][8] = {};
  float lsum[2][4] = {};

  const size_t kpb = (size_t)bh * 4096 * 128;
  const size_t vtb = (size_t)bh * 128 * 4096;
  const int n_tiles = 4*sblk + 100;   // tiles of 32 t
  const int n_safe  = n_tiles - 4;    // last 4 tiles need causal masking

  // staging: 512 16B-chunks per K tile and per V tile; each wave does 2+2
  // LDS dest linear in lane (DMA requirement); swizzle applied on global src.
  auto issue = [&](int buf, int t0) {
#pragma unroll
    for (int kk = 0; kk < 2; kk++) {
      int j = (w*2 + kk)*64 + lane;          // chunk index 0..511
      int r = j >> 4, p = j & 15, c = p ^ (r & 7);
      g2lds16(&Kp[kpb + (size_t)(t0 + r) * 128 + c*8],
              (unsigned short*)&Ks[buf][0][0] + (size_t)j * 8);
    }
#pragma unroll
    for (int kk = 0; kk < 2; kk++) {
      int j = (w*2 + kk)*64 + lane;
      int r = j >> 2, p = j & 3, c = p ^ ((r >> 1) & 3);
      g2lds16(&Vt[vtb + (size_t)r * 4096 + t0 + c*8],
              (unsigned short*)&Vs[buf][0][0] + (size_t)j * 8);
    }
  };

  int buf = 0;
  issue(0, tpar * 32);

  for (int it = tpar; it < n_tiles; it += 3) {
    __syncthreads();                       // drains loads for `buf`
    if (it + 3 < n_tiles) issue(buf ^ 1, (it + 3) * 32);   // overlap with compute

    // QK^T  (32 t-cols per tile: nc = 0,1)
    f32x4 sacc[2][2] = {};
    __builtin_amdgcn_s_setprio(1);
#pragma unroll
    for (int kc = 0; kc < 4; kc++) {
      bf16x8 kf[2];
#pragma unroll
      for (int nc = 0; nc < 2; nc++)
        kf[nc] = *(const bf16x8*)&Ks[buf][nc*16 + l15][((kc*4 + q) ^ (l15 & 7)) * 8];
#pragma unroll
      for (int mi = 0; mi < 2; mi++)
#pragma unroll
        for (int nc = 0; nc < 2; nc++)
          sacc[mi][nc] = __builtin_amdgcn_mfma_f32_16x16x32_bf16(qf[mi][kc], kf[nc], sacc[mi][nc], 0, 0, 0);
    }
    __builtin_amdgcn_s_setprio(0);

    // exp2 + P store (pad-spread, conflict-free), mask only last 4 tiles
    const bool safe = (it < n_safe);
    const int t0 = it << 5;
#pragma unroll
    for (int mi = 0; mi < 2; mi++)
#pragma unroll
      for (int r = 0; r < 4; r++) {
        const int rr = mi*16 + q*4 + r;
        const int rel = s0 + w*32 + rr + CCH - t0;
        float ls = 0.f;
#pragma unroll
        for (int nc = 0; nc < 2; nc++) {
          float p;
          asm("v_exp_f32 %0, %1" : "=v"(p) : "v"(sacc[mi][nc][r]));   // 2^x; log2e folded into Qp
          if (!safe && (nc*16 + l15 > rel)) p = 0.f;
          ls += p;
          Ps[w][rr][nc*16 + l15] = f2bf_cvt(p);
        }
        lsum[mi][r] += ls;
      }

    // PV (single 32-k chunk)
    bf16x8 pf[2];
#pragma unroll
    for (int mi = 0; mi < 2; mi++)
      pf[mi] = *(const bf16x8*)&Ps[w][mi*16 + l15][q*8];
    __builtin_amdgcn_s_setprio(1);
#pragma unroll
    for (int dc = 0; dc < 8; dc++) {
      int d2 = dc*16 + l15;
      bf16x8 vfr = *(const bf16x8*)&Vs[buf][d2][(q ^ ((d2 >> 1) & 3)) * 8];
#pragma unroll
      for (int mi = 0; mi < 2; mi++)
        oacc[mi][dc] = __builtin_amdgcn_mfma_f32_16x16x32_bf16(pf[mi], vfr, oacc[mi][dc], 0, 0, 0);
    }
    __builtin_amdgcn_s_setprio(0);
    buf ^= 1;
  }

  // write partials
  const size_t pb = ((size_t)tpar * 32 + bh) * 1024 + s0 + w*32;
#pragma unroll
  for (int mi = 0; mi < 2; mi++)
#pragma unroll
    for (int r = 0; r < 4; r++) {
      float l = lsum[mi][r];
      l += __shfl_xor(l, 1, 64);
      l += __shfl_xor(l, 2, 64);
      l += __shfl_xor(l, 4, 64);
      l += __shfl_xor(l, 8, 64);
      if (l15 == 0) Lpart[pb + mi*16 + q*4 + r] = l;
    }
#pragma unroll
  for (int mi = 0; mi < 2; mi++)
#pragma unroll
    for (int dc = 0; dc < 8; dc++)
#pragma unroll
      for (int r = 0; r < 4; r++)
        Opart[(pb + mi*16 + q*4 + r) * 128 + dc*16 + l15] = oacc[mi][dc][r];
}

// ---------- combine 3 partials -> Ao bf16 [m][2048] ----------
__global__ __launch_bounds__(256) void attn_combine_kernel(
    const float* __restrict__ Opart, const float* __restrict__ Lpart,
    unsigned short* __restrict__ Ao)
{
  const size_t TS = 4194304ull;   // tpar stride in floats (32*1024*128)
  int gid = blockIdx.x * 256 + threadIdx.x;
  int idx = gid * 8;              // over 2048*2048
  int m = idx >> 11, n0 = idx & 2047;
  int b = m >> 10, s = m & 1023;
  int h, d2_0;
  if (n0 < 1024) { h = n0 >> 6; d2_0 = n0 & 63; }
  else { h = (n0 - 1024) >> 6; d2_0 = 64 + ((n0 - 1024) & 63); }
  int bh = b*16 + h;
  size_t ob = ((size_t)bh * 1024 + s) * 128 + d2_0;
  float l0 = Lpart[(size_t)bh * 1024 + s];
  float l1 = Lpart[32768 + (size_t)bh * 1024 + s];
  float l2 = Lpart[65536 + (size_t)bh * 1024 + s];
  float inv = 1.f / (l0 + l1 + l2);
  float4 x0 = *(const float4*)&Opart[ob];
  float4 x1 = *(const float4*)&Opart[ob + 4];
  float4 y0 = *(const float4*)&Opart[ob + TS];
  float4 y1 = *(const float4*)&Opart[ob + TS + 4];
  float4 z0 = *(const float4*)&Opart[ob + 2*TS];
  float4 z1 = *(const float4*)&Opart[ob + 2*TS + 4];
  US8 o;
  o.u[0] = f2bf((x0.x + y0.x + z0.x) * inv); o.u[1] = f2bf((x0.y + y0.y + z0.y) * inv);
  o.u[2] = f2bf((x0.z + y0.z + z0.z) * inv); o.u[3] = f2bf((x0.w + y0.w + z0.w) * inv);
  o.u[4] = f2bf((x1.x + y1.x + z1.x) * inv); o.u[5] = f2bf((x1.y + y1.y + z1.y) * inv);
  o.u[6] = f2bf((x1.z + y1.z + z1.z) * inv); o.u[7] = f2bf((x1.w + y1.w + z1.w) * inv);
  *(US8*)&Ao[idx] = o;
}

// ---------- launch ----------
extern "C" void kernel_launch(void* const* d_in, const int* in_sizes, int n_in,
                              void* d_out, int out_size, void* d_ws, size_t ws_size,
                              hipStream_t stream)
{
  (void)in_sizes; (void)n_in; (void)out_size; (void)ws_size;
  const float* hre = (const float*)d_in[0];
  const float* him = (const float*)d_in[1];
  const float* Kcr = (const float*)d_in[2];
  const float* Kci = (const float*)d_in[3];
  const float* Vcr = (const float*)d_in[4];
  const float* Vci = (const float*)d_in[5];
  const float* gamma = (const float*)d_in[6];
  const float* bre = (const float*)d_in[7];
  const float* bim = (const float*)d_in[8];
  const float* qWr = (const float*)d_in[9];
  const float* qWi = (const float*)d_in[10];
  const float* qbr = (const float*)d_in[11];
  const float* qbi = (const float*)d_in[12];
  const float* kWr = (const float*)d_in[13];
  const float* kWi = (const float*)d_in[14];
  const float* kbr = (const float*)d_in[15];
  const float* kbi = (const float*)d_in[16];
  const float* vWr = (const float*)d_in[17];
  const float* vWi = (const float*)d_in[18];
  const float* vbr = (const float*)d_in[19];
  const float* vbi = (const float*)d_in[20];
  const float* oWr = (const float*)d_in[21];
  const float* oWi = (const float*)d_in[22];
  const float* obr = (const float*)d_in[23];
  const float* obi = (const float*)d_in[24];
  float* out = (float*)d_out;

  char* ws = (char*)d_ws;
  size_t off = 0;
  auto carve = [&](size_t bytes) {
    char* p = ws + off;
    off += (bytes + 255) & ~(size_t)255;
    return p;
  };
  unsigned short* Aln  = (unsigned short*)carve(2048ull * 2048 * 2);       // 8 MB (dead after gemm_qkv; reused as Ao)
  unsigned short* Wc   = (unsigned short*)carve(4ull * 2048 * 2048 * 2);   // 32 MB
  float*          bc   = (float*)carve(4ull * 2048 * 4);                   // 32 KB
  unsigned short* Qp   = (unsigned short*)carve(4194304ull * 2);           // 8 MB
  unsigned short* Kp   = (unsigned short*)carve(16777216ull * 2);          // 32 MB
  unsigned short* Vt   = (unsigned short*)carve(16777216ull * 2);          // 32 MB
  float*          Opart= (float*)carve(3ull * 32 * 1024 * 128 * 4);        // 48 MB
  float*          Lpart= (float*)carve(3ull * 32 * 1024 * 4);              // 384 KB

  unsigned short* Ao = Aln;   // alias: Aln dead after gemm_qkv, combine runs later

  // output chunk offsets (floats)
  float* out_Kre = out + 4194304;
  float* out_Kim = out + 4194304 + 8388608;
  float* out_Vre = out + 4194304 + 2 * 8388608;
  float* out_Vim = out + 4194304 + 3 * 8388608;

  hipLaunchKernelGGL(ln_kernel, dim3(2048), dim3(256), 0, stream,
                     hre, him, gamma, bre, bim, Aln);
  hipLaunchKernelGGL(wprep_kernel, dim3(8192), dim3(256), 0, stream,
                     qWr, qWi, kWr, kWi, vWr, vWi, oWr, oWi, Wc);
  hipLaunchKernelGGL(bprep_kernel, dim3(32), dim3(256), 0, stream,
                     qbr, qbi, kbr, kbi, vbr, vbi, obr, obi, bc);
  hipLaunchKernelGGL(gemm_qkv_kernel, dim3(48, 16), dim3(256), 0, stream,
                     Aln, Wc, bc, Qp, Kp, out_Kre, out_Kim, out_Vre, out_Vim);
  hipLaunchKernelGGL(pack_kcache_kernel, dim3(384, 32), dim3(256), 0, stream,
                     Kcr, Kci, Kp, out_Kre, out_Kim);
  hipLaunchKernelGGL(pack_vt_fused_kernel, dim3(2048), dim3(256), 0, stream,
                     Vcr, Vci, out_Vre, out_Vim, Vt);
  hipLaunchKernelGGL(attn_kernel, dim3(32, 8, 3), dim3(256), 0, stream,
                     Qp, Kp, Vt, Opart, Lpart);
  hipLaunchKernelGGL(attn_combine_kernel, dim3(2048), dim3(256), 0, stream,
                     Opart, Lpart, Ao);
  hipLaunchKernelGGL(gemm_oproj_kernel, dim3(16, 16), dim3(256), 0, stream,
                     Ao, Wc + 3ull * 2048 * 2048, bc + 3 * 2048, hre, him, out);
}

// Round 5
// 571.182 us; speedup vs baseline: 1.0686x; 1.0015x over previous
//
#include <hip/hip_runtime.h>
#include <hip/hip_bf16.h>
#include <cstdint>
#include <cstddef>

// ---------- types ----------
typedef __bf16 bf16x8 __attribute__((ext_vector_type(8)));
typedef float  f32x4  __attribute__((ext_vector_type(4)));

__device__ __forceinline__ unsigned short f2bf(float f) {
  union { float f; unsigned u; } v; v.f = f;
  unsigned u = v.u;
  u += 0x7FFFu + ((u >> 16) & 1u);   // RNE
  return (unsigned short)(u >> 16);
}

__device__ __forceinline__ unsigned short f2bf_cvt(float f) {
  __bf16 h = (__bf16)f;
  return __builtin_bit_cast(unsigned short, h);
}

__device__ __forceinline__ int imin(int a, int b) { return a < b ? a : b; }

struct alignas(16) US8 { unsigned short u[8]; };

__device__ __forceinline__ void g2lds16(const void* g, void* l) {
  __builtin_amdgcn_global_load_lds(
      (const __attribute__((address_space(1))) unsigned int*)g,
      (__attribute__((address_space(3))) unsigned int*)l, 16, 0, 0);
}

// sizes
#define BB 2
#define SS 1024
#define HID 1024
#define NHH 16
#define HDD 64
#define TT 4096
#define CCH 3072
// Q pre-scale: 1/sqrt(64) * log2(e)  (scores then exponentiated with raw v_exp_f32 = 2^x)
#define QSCALE (0.125f * 1.44269504088896f)

// ---------- merged prep: wprep (blocks 0..8191) + ln (8192..10239) + bprep (10240..10271) ----------
__global__ __launch_bounds__(256) void prep_kernel(
    const float* __restrict__ hre, const float* __restrict__ him,
    const float* __restrict__ gamma, const float* __restrict__ bre,
    const float* __restrict__ bim, unsigned short* __restrict__ Aln,
    const float* __restrict__ qWr, const float* __restrict__ qWi,
    const float* __restrict__ kWr, const float* __restrict__ kWi,
    const float* __restrict__ vWr, const float* __restrict__ vWi,
    const float* __restrict__ oWr, const float* __restrict__ oWi,
    unsigned short* __restrict__ Wc,
    const float* __restrict__ qbr, const float* __restrict__ qbi,
    const float* __restrict__ kbr, const float* __restrict__ kbi,
    const float* __restrict__ vbr, const float* __restrict__ vbi,
    const float* __restrict__ obr, const float* __restrict__ obi,
    float* __restrict__ bc)
{
  const int bid = blockIdx.x;
  const int tid = threadIdx.x;
  if (bid < 8192) {
    // ---- wprep ----
    int gid = bid * 256 + tid;
    int idx = gid * 8;                     // over 4*2048*2048
    int p   = idx >> 22;
    int rem = idx & 0x3FFFFF;
    int n   = rem >> 11;
    int k   = rem & 2047;
    const float* Wr; const float* Wi;
    switch (p) {
      case 0:  Wr = qWr; Wi = qWi; break;
      case 1:  Wr = kWr; Wi = kWi; break;
      case 2:  Wr = vWr; Wi = vWi; break;
      default: Wr = oWr; Wi = oWi; break;
    }
    const float* src; float sgn = 1.f;
    if (n < 1024) {
      if (k < 1024) src = Wr + (size_t)n * 1024 + k;
      else        { src = Wi + (size_t)n * 1024 + (k - 1024); sgn = -1.f; }
    } else {
      if (k < 1024) src = Wi + (size_t)(n - 1024) * 1024 + k;
      else          src = Wr + (size_t)(n - 1024) * 1024 + (k - 1024);
    }
    float4 a = ((const float4*)src)[0];
    float4 b = ((const float4*)src)[1];
    US8 o;
    o.u[0] = f2bf(a.x * sgn); o.u[1] = f2bf(a.y * sgn);
    o.u[2] = f2bf(a.z * sgn); o.u[3] = f2bf(a.w * sgn);
    o.u[4] = f2bf(b.x * sgn); o.u[5] = f2bf(b.y * sgn);
    o.u[6] = f2bf(b.z * sgn); o.u[7] = f2bf(b.w * sgn);
    *(US8*)&Wc[idx] = o;
  } else if (bid < 10240) {
    // ---- layernorm ----
    int m = bid - 8192;
    const float4 vr = ((const float4*)(hre + (size_t)m * HID))[tid];
    const float4 vi = ((const float4*)(him + (size_t)m * HID))[tid];
    float sr = vr.x + vr.y + vr.z + vr.w;
    float si = vi.x + vi.y + vi.z + vi.w;
    float sq = vr.x*vr.x + vr.y*vr.y + vr.z*vr.z + vr.w*vr.w
             + vi.x*vi.x + vi.y*vi.y + vi.z*vi.z + vi.w*vi.w;
    __shared__ float red[3][4];
    int lane = tid & 63, w = tid >> 6;
    for (int off = 32; off; off >>= 1) {
      sr += __shfl_down(sr, off, 64);
      si += __shfl_down(si, off, 64);
      sq += __shfl_down(sq, off, 64);
    }
    if (lane == 0) { red[0][w] = sr; red[1][w] = si; red[2][w] = sq; }
    __syncthreads();
    sr = red[0][0] + red[0][1] + red[0][2] + red[0][3];
    si = red[1][0] + red[1][1] + red[1][2] + red[1][3];
    sq = red[2][0] + red[2][1] + red[2][2] + red[2][3];
    float mur = sr * (1.f/1024.f), mui = si * (1.f/1024.f);
    float var = sq * (1.f/1024.f) - mur*mur - mui*mui;
    float inv = rsqrtf(var + 1e-5f);
    int k = tid * 4;
    float4 g  = ((const float4*)gamma)[tid];
    float4 br = ((const float4*)bre)[tid];
    float4 bi = ((const float4*)bim)[tid];
    ushort4 nr, ni;
    nr.x = f2bf((vr.x - mur) * inv * g.x + br.x);
    nr.y = f2bf((vr.y - mur) * inv * g.y + br.y);
    nr.z = f2bf((vr.z - mur) * inv * g.z + br.z);
    nr.w = f2bf((vr.w - mur) * inv * g.w + br.w);
    ni.x = f2bf((vi.x - mui) * inv * g.x + bi.x);
    ni.y = f2bf((vi.y - mui) * inv * g.y + bi.y);
    ni.z = f2bf((vi.z - mui) * inv * g.z + bi.z);
    ni.w = f2bf((vi.w - mui) * inv * g.w + bi.w);
    *(ushort4*)&Aln[(size_t)m * 2048 + k]        = nr;
    *(ushort4*)&Aln[(size_t)m * 2048 + 1024 + k] = ni;
  } else {
    // ---- bias prep ----
    int idx = (bid - 10240) * 256 + tid;  // 8192
    int p = idx >> 11, n = idx & 2047;
    const float* br; const float* bi;
    switch (p) {
      case 0:  br = qbr; bi = qbi; break;
      case 1:  br = kbr; bi = kbi; break;
      case 2:  br = vbr; bi = vbi; break;
      default: br = obr; bi = obi; break;
    }
    bc[idx] = (n < 1024) ? br[n] : bi[n - 1024];
  }
}

// ---------- QKV GEMM (blocks 0..767) merged with K-cache pack (768..13055) ----------
// GEMM: 3-buffer global_load_lds pipeline, counted vmcnt, XOR chunk swizzle.
// Pack blocks are independent streaming work that backfills CU slack.
__global__ __launch_bounds__(256) void gemm_qkv_pack_kernel(
    const unsigned short* __restrict__ A, const unsigned short* __restrict__ Bm,
    const float* __restrict__ bias,
    unsigned short* __restrict__ Qp, unsigned short* __restrict__ Kp,
    float* __restrict__ out_Kre, float* __restrict__ out_Kim,
    float* __restrict__ out_Vre, float* __restrict__ out_Vim,
    const float* __restrict__ Kcr, const float* __restrict__ Kci)
{
  __shared__ alignas(16) unsigned short As[3][128][32];   // 24 KB
  __shared__ alignas(16) unsigned short Bs[3][128][32];   // 24 KB
  const int tid = threadIdx.x;
  if (blockIdx.x >= 768) {
    // ---- pack_kcache: cache -> Kp bf16 [bh][t<3072][128] + out_K f32 ----
    int pk = blockIdx.x - 768;
    int bh = pk / 384;
    int xx = pk % 384;
    int idx = (xx * 256 + tid) * 4;   // over 3072*128
    int d2 = idx & 127;
    int t  = idx >> 7;                // 0..3071
    int b = bh >> 4, h = bh & 15;
    int d = d2 & 63;
    bool im = d2 >= 64;
    const float* src = im ? Kci : Kcr;
    float4 v = *(const float4*)&src[(((size_t)b * CCH + t) * 16 + h) * 64 + d];
    ushort4 o;
    o.x = f2bf(v.x); o.y = f2bf(v.y); o.z = f2bf(v.z); o.w = f2bf(v.w);
    *(ushort4*)&Kp[((size_t)bh * 4096 + t) * 128 + d2] = o;
    float* dst = im ? out_Kim : out_Kre;
    *(float4*)&dst[(((size_t)b * 4096 + t) * 16 + h) * 64 + d] = v;
    return;
  }
  // ---- GEMM ----
  const int K = 2048;
  const int NT = K / 32;   // 64
  int bm = (blockIdx.x / 48) * 128;
  int bn = (blockIdx.x % 48) * 128;
  int lane = tid & 63, w = tid >> 6;
  int wm = (w >> 1) * 64, wn = (w & 1) * 64;
  int l15 = lane & 15, q = lane >> 4;
  int lr = tid >> 2;                         // staged row 0..63
  int lcs = ((tid & 3) ^ ((tid >> 3) & 3)) * 8;  // source chunk, XOR-swizzled

  const unsigned short* A0 = A  + (size_t)(bm + lr)      * K + lcs;
  const unsigned short* A1 = A  + (size_t)(bm + lr + 64) * K + lcs;
  const unsigned short* B0 = Bm + (size_t)(bn + lr)      * K + lcs;
  const unsigned short* B1 = Bm + (size_t)(bn + lr + 64) * K + lcs;
  const int rsw = ((l15 >> 1) & 3);          // read-side XOR

  f32x4 acc[4][4] = {};

  auto stage = [&](int b, int t) {
    int k0 = t * 32;
    g2lds16(A0 + k0, (unsigned short*)As[b] + 8*tid);
    g2lds16(A1 + k0, (unsigned short*)As[b] + 2048 + 8*tid);
    g2lds16(B0 + k0, (unsigned short*)Bs[b] + 8*tid);
    g2lds16(B1 + k0, (unsigned short*)Bs[b] + 2048 + 8*tid);
  };

  stage(0, 0);
  stage(1, 1);

  int bc_ = 0, bp_ = 2;
  for (int t = 0; t < NT; ++t) {
    if (t + 1 < NT) asm volatile("s_waitcnt vmcnt(4)" ::: "memory");
    else            asm volatile("s_waitcnt vmcnt(0)" ::: "memory");
    __builtin_amdgcn_s_barrier();
    __builtin_amdgcn_sched_barrier(0);
    if (t + 2 < NT) stage(bp_, t + 2);

    bf16x8 af[4], bfr[4];
#pragma unroll
    for (int i = 0; i < 4; i++) af[i]  = *(const bf16x8*)&As[bc_][wm + i*16 + l15][(q ^ rsw) * 8];
#pragma unroll
    for (int i = 0; i < 4; i++) bfr[i] = *(const bf16x8*)&Bs[bc_][wn + i*16 + l15][(q ^ rsw) * 8];
#pragma unroll
    for (int i = 0; i < 4; i++)
#pragma unroll
      for (int j = 0; j < 4; j++)
        acc[i][j] = __builtin_amdgcn_mfma_f32_16x16x32_bf16(af[i], bfr[j], acc[i][j], 0, 0, 0);

    bc_ = (bc_ == 2) ? 0 : bc_ + 1;
    bp_ = (bp_ == 2) ? 0 : bp_ + 1;
  }

  const int sec = bn >> 11;   // 0=Q, 1=K, 2=V
#pragma unroll
  for (int i = 0; i < 4; i++)
#pragma unroll
    for (int j = 0; j < 4; j++) {
      int n = bn + wn + j*16 + l15;
      float bv = bias[n];
      int col = n & 2047;
      int re = (col < 1024) ? 1 : 0;
      int h = (col & 1023) >> 6, d = col & 63;
      int d2 = re ? d : 64 + d;
#pragma unroll
      for (int r = 0; r < 4; r++) {
        int m = bm + wm + i*16 + q*4 + r;
        float val = acc[i][j][r] + bv;
        int b = m >> 10, s = m & 1023;
        int bh = b*16 + h;
        if (sec == 0) {
          Qp[((size_t)bh*1024 + s)*128 + d2] = f2bf(val * QSCALE);
        } else if (sec == 1) {
          int t = CCH + s;
          Kp[((size_t)bh*4096 + t)*128 + d2] = f2bf(val);
          float* dst = re ? out_Kre : out_Kim;
          dst[(((size_t)b*4096 + t)*16 + h)*64 + d] = val;
        } else {
          int t = CCH + s;
          float* dst = re ? out_Vre : out_Vim;
          dst[(((size_t)b*4096 + t)*16 + h)*64 + d] = val;
        }
      }
    }
}

// ---------- o-proj GEMM with residual + split write (pipelined) ----------
__global__ __launch_bounds__(256) void gemm_oproj_kernel(
    const unsigned short* __restrict__ A, const unsigned short* __restrict__ Bm,
    const float* __restrict__ bias, const float* __restrict__ hre,
    const float* __restrict__ him, float* __restrict__ out)
{
  __shared__ alignas(16) unsigned short As[3][128][32];
  __shared__ alignas(16) unsigned short Bs[3][128][32];
  const int K = 2048;
  const int NT = K / 32;
  int bm = blockIdx.y * 128;
  int bn = blockIdx.x * 128;
  int tid = threadIdx.x;
  int lane = tid & 63, w = tid >> 6;
  int wm = (w >> 1) * 64, wn = (w & 1) * 64;
  int l15 = lane & 15, q = lane >> 4;
  int lr = tid >> 2;
  int lcs = ((tid & 3) ^ ((tid >> 3) & 3)) * 8;

  const unsigned short* A0 = A  + (size_t)(bm + lr)      * K + lcs;
  const unsigned short* A1 = A  + (size_t)(bm + lr + 64) * K + lcs;
  const unsigned short* B0 = Bm + (size_t)(bn + lr)      * K + lcs;
  const unsigned short* B1 = Bm + (size_t)(bn + lr + 64) * K + lcs;
  const int rsw = ((l15 >> 1) & 3);

  f32x4 acc[4][4] = {};

  auto stage = [&](int b, int t) {
    int k0 = t * 32;
    g2lds16(A0 + k0, (unsigned short*)As[b] + 8*tid);
    g2lds16(A1 + k0, (unsigned short*)As[b] + 2048 + 8*tid);
    g2lds16(B0 + k0, (unsigned short*)Bs[b] + 8*tid);
    g2lds16(B1 + k0, (unsigned short*)Bs[b] + 2048 + 8*tid);
  };

  stage(0, 0);
  stage(1, 1);

  int bc_ = 0, bp_ = 2;
  for (int t = 0; t < NT; ++t) {
    if (t + 1 < NT) asm volatile("s_waitcnt vmcnt(4)" ::: "memory");
    else            asm volatile("s_waitcnt vmcnt(0)" ::: "memory");
    __builtin_amdgcn_s_barrier();
    __builtin_amdgcn_sched_barrier(0);
    if (t + 2 < NT) stage(bp_, t + 2);

    bf16x8 af[4], bfr[4];
#pragma unroll
    for (int i = 0; i < 4; i++) af[i]  = *(const bf16x8*)&As[bc_][wm + i*16 + l15][(q ^ rsw) * 8];
#pragma unroll
    for (int i = 0; i < 4; i++) bfr[i] = *(const bf16x8*)&Bs[bc_][wn + i*16 + l15][(q ^ rsw) * 8];
#pragma unroll
    for (int i = 0; i < 4; i++)
#pragma unroll
      for (int j = 0; j < 4; j++)
        acc[i][j] = __builtin_amdgcn_mfma_f32_16x16x32_bf16(af[i], bfr[j], acc[i][j], 0, 0, 0);

    bc_ = (bc_ == 2) ? 0 : bc_ + 1;
    bp_ = (bp_ == 2) ? 0 : bp_ + 1;
  }

#pragma unroll
  for (int i = 0; i < 4; i++)
#pragma unroll
    for (int j = 0; j < 4; j++) {
      int n = bn + wn + j*16 + l15;
      float bv = bias[n];
#pragma unroll
      for (int r = 0; r < 4; r++) {
        int m = bm + wm + i*16 + q*4 + r;
        float val = acc[i][j][r] + bv;
        if (n < 1024) out[(size_t)m * 1024 + n] = val + hre[(size_t)m * 1024 + n];
        else out[2097152 + (size_t)m * 1024 + (n - 1024)] = val + him[(size_t)m * 1024 + (n - 1024)];
      }
    }
}

// ---------- fused V: cache -> out_V f32 (+readback of new part) -> Vt bf16 [bh][d2][t] ----------
__global__ __launch_bounds__(256) void pack_vt_fused_kernel(
    const float* __restrict__ Vc_re, const float* __restrict__ Vc_im,
    float* __restrict__ out_Vre, float* __restrict__ out_Vim,
    unsigned short* __restrict__ Vt)
{
  __shared__ float Ts[64][136];
  const int ty = blockIdx.x & 63;   // t-tile
  const int bh = blockIdx.x >> 6;   // 0..31
  const int b = bh >> 4, h = bh & 15;
  const int t0 = ty * 64;
  const int tid = threadIdx.x;
#pragma unroll
  for (int rr = 0; rr < 8; rr++) {
    int j = rr * 256 + tid;
    int t_loc = j >> 5, c = j & 31;
    int d2 = c * 4;
    int t = t0 + t_loc;
    int d = (d2 < 64) ? d2 : d2 - 64;
    float4 v;
    if (t < CCH) {
      const float* src = (d2 < 64) ? Vc_re : Vc_im;
      v = *(const float4*)&src[(((size_t)b * CCH + t) * 16 + h) * 64 + d];
      float* dst = (d2 < 64) ? out_Vre : out_Vim;
      *(float4*)&dst[(((size_t)b * 4096 + t) * 16 + h) * 64 + d] = v;
    } else {
      const float* src = (d2 < 64) ? out_Vre : out_Vim;   // written by gemm_qkv
      v = *(const float4*)&src[(((size_t)b * 4096 + t) * 16 + h) * 64 + d];
    }
    *(float4*)&Ts[t_loc][d2] = v;
  }
  __syncthreads();
  const int d2 = tid >> 1, half = tid & 1;
  unsigned short tmp[32];
#pragma unroll
  for (int i = 0; i < 32; i++) tmp[i] = f2bf(Ts[half*32 + i][d2]);
  size_t dst = (size_t)bh * 128 * 4096 + (size_t)d2 * 4096 + t0 + half*32;
#pragma unroll
  for (int kq = 0; kq < 4; kq++)
    *(US8*)&Vt[dst + kq*8] = *(US8*)&tmp[kq*8];
}

// ---------- flash attention: 128 q-rows/block, T=32 tiles, 3-way t-split ----------
// Counted-vmcnt pipeline: Ks 3-buffer (prefetch distance 2), Vs 2-buffer with
// split wait (V confirmed just before PV, after QK^T+softmax cover its latency).
// Per-wave per-iter issues: 2 K-loads then 2 V-loads -> vmcnt(4) at top retires
// K(i); vmcnt(4) before PV retires V(i). Issues unconditional w/ clamped addr.
// LDS = 24K + 16K + 10K = 50 KB -> 3 blocks/CU kept.
__global__ __launch_bounds__(256) void attn_kernel(
    const unsigned short* __restrict__ Qp, const unsigned short* __restrict__ Kp,
    const unsigned short* __restrict__ Vt, float* __restrict__ Opart,
    float* __restrict__ Lpart)
{
  const int bh   = blockIdx.x;   // 0..31
  const int sblk = blockIdx.y;   // 0..7
  const int tpar = blockIdx.z;   // 0..2
  const int s0 = sblk * 128;
  const int tid = threadIdx.x;
  const int lane = tid & 63, w = tid >> 6;
  const int l15 = lane & 15, q = lane >> 4;

  __shared__ alignas(16) unsigned short Ks[3][32][128];  // 24 KB
  __shared__ alignas(16) unsigned short Vs[2][128][32];  // 16 KB
  __shared__ alignas(16) unsigned short Ps[4][32][40];   // 10 KB

  // persistent Q fragments
  bf16x8 qf[2][4];
#pragma unroll
  for (int mi = 0; mi < 2; mi++) {
    const size_t qb = ((size_t)bh * 1024 + s0 + w*32 + mi*16 + l15) * 128;
#pragma unroll
    for (int kc = 0; kc < 4; kc++)
      qf[mi][kc] = *(const bf16x8*)&Qp[qb + kc*32 + q*8];
  }

  f32x4 oacc[2][8] = {};
  float lsum[2][4] = {};

  const size_t kpb = (size_t)bh * 4096 * 128;
  const size_t vtb = (size_t)bh * 128 * 4096;
  const int n_tiles = 4*sblk + 100;   // tiles of 32 t
  const int n_safe  = n_tiles - 4;

  auto issueK = [&](int slot, int t0) {
#pragma unroll
    for (int kk = 0; kk < 2; kk++) {
      int j = (w*2 + kk)*64 + lane;          // chunk 0..511
      int r = j >> 4, p = j & 15, c = p ^ (r & 7);
      g2lds16(&Kp[kpb + (size_t)(t0 + r) * 128 + c*8],
              (unsigned short*)&Ks[slot][0][0] + (size_t)j * 8);
    }
  };
  auto issueV = [&](int slot, int t0) {
#pragma unroll
    for (int kk = 0; kk < 2; kk++) {
      int j = (w*2 + kk)*64 + lane;
      int r = j >> 2, p = j & 3, c = p ^ ((r >> 1) & 3);
      g2lds16(&Vt[vtb + (size_t)r * 4096 + t0 + c*8],
              (unsigned short*)&Vs[slot][0][0] + (size_t)j * 8);
    }
  };

  // prologue: per wave issue K(0), K(1), V(0)  (6 loads)
  const int t00 = tpar * 32;
  issueK(0, t00);
  issueK(1, imin((tpar + 3) * 32, 4064));
  issueV(0, t00);

  int kcur = 0, vcur = 0;
  for (int it = tpar; it < n_tiles; it += 3) {
    asm volatile("s_waitcnt vmcnt(4)" ::: "memory");   // K(i) landed
    __builtin_amdgcn_s_barrier();
    __builtin_amdgcn_sched_barrier(0);
    {
      int kslot = (kcur >= 1) ? kcur - 1 : kcur + 2;   // (kcur+2)%3
      issueK(kslot, imin((it + 6) * 32, 4064));
      issueV(vcur ^ 1, imin((it + 3) * 32, 4064));
    }

    // QK^T (reads Ks[kcur])
    f32x4 sacc[2][2] = {};
    __builtin_amdgcn_s_setprio(1);
#pragma unroll
    for (int kc = 0; kc < 4; kc++) {
      bf16x8 kf[2];
#pragma unroll
      for (int nc = 0; nc < 2; nc++)
        kf[nc] = *(const bf16x8*)&Ks[kcur][nc*16 + l15][((kc*4 + q) ^ (l15 & 7)) * 8];
#pragma unroll
      for (int mi = 0; mi < 2; mi++)
#pragma unroll
        for (int nc = 0; nc < 2; nc++)
          sacc[mi][nc] = __builtin_amdgcn_mfma_f32_16x16x32_bf16(qf[mi][kc], kf[nc], sacc[mi][nc], 0, 0, 0);
    }
    __builtin_amdgcn_s_setprio(0);

    // exp2 + P store, mask only last 4 tiles
    const bool safe = (it < n_safe);
    const int t0 = it << 5;
#pragma unroll
    for (int mi = 0; mi < 2; mi++)
#pragma unroll
      for (int r = 0; r < 4; r++) {
        const int rr = mi*16 + q*4 + r;
        const int rel = s0 + w*32 + rr + CCH - t0;
        float ls = 0.f;
#pragma unroll
        for (int nc = 0; nc < 2; nc++) {
          float p;
          asm("v_exp_f32 %0, %1" : "=v"(p) : "v"(sacc[mi][nc][r]));   // 2^x
          if (!safe && (nc*16 + l15 > rel)) p = 0.f;
          ls += p;
          Ps[w][rr][nc*16 + l15] = f2bf_cvt(p);
        }
        lsum[mi][r] += ls;
      }

    // V(i) landed: retire previous iter's {K,V} pair (keeps this iter's 4 newest)
    asm volatile("s_waitcnt vmcnt(4)" ::: "memory");
    __builtin_amdgcn_sched_barrier(0);

    // PV (reads Vs[vcur])
    bf16x8 pf[2];
#pragma unroll
    for (int mi = 0; mi < 2; mi++)
      pf[mi] = *(const bf16x8*)&Ps[w][mi*16 + l15][q*8];
    __builtin_amdgcn_s_setprio(1);
#pragma unroll
    for (int dc = 0; dc < 8; dc++) {
      int d2 = dc*16 + l15;
      bf16x8 vfr = *(const bf16x8*)&Vs[vcur][d2][(q ^ ((d2 >> 1) & 3)) * 8];
#pragma unroll
      for (int mi = 0; mi < 2; mi++)
        oacc[mi][dc] = __builtin_amdgcn_mfma_f32_16x16x32_bf16(pf[mi], vfr, oacc[mi][dc], 0, 0, 0);
    }
    __builtin_amdgcn_s_setprio(0);

    kcur = (kcur == 2) ? 0 : kcur + 1;
    vcur ^= 1;
  }

  // drain in-flight DMA before LDS deallocation at kernel end
  asm volatile("s_waitcnt vmcnt(0)" ::: "memory");

  // write partials
  const size_t pb = ((size_t)tpar * 32 + bh) * 1024 + s0 + w*32;
#pragma unroll
  for (int mi = 0; mi < 2; mi++)
#pragma unroll
    for (int r = 0; r < 4; r++) {
      float l = lsum[mi][r];
      l += __shfl_xor(l, 1, 64);
      l += __shfl_xor(l, 2, 64);
      l += __shfl_xor(l, 4, 64);
      l += __shfl_xor(l, 8, 64);
      if (l15 == 0) Lpart[pb + mi*16 + q*4 + r] = l;
    }
#pragma unroll
  for (int mi = 0; mi < 2; mi++)
#pragma unroll
    for (int dc = 0; dc < 8; dc++)
#pragma unroll
      for (int r = 0; r < 4; r++)
        Opart[(pb + mi*16 + q*4 + r) * 128 + dc*16 + l15] = oacc[mi][dc][r];
}

// ---------- combine 3 partials -> Ao bf16 [m][2048] ----------
__global__ __launch_bounds__(256) void attn_combine_kernel(
    const float* __restrict__ Opart, const float* __restrict__ Lpart,
    unsigned short* __restrict__ Ao)
{
  const size_t TS = 4194304ull;   // tpar stride in floats (32*1024*128)
  int gid = blockIdx.x * 256 + threadIdx.x;
  int idx = gid * 8;              // over 2048*2048
  int m = idx >> 11, n0 = idx & 2047;
  int b = m >> 10, s = m & 1023;
  int h, d2_0;
  if (n0 < 1024) { h = n0 >> 6; d2_0 = n0 & 63; }
  else { h = (n0 - 1024) >> 6; d2_0 = 64 + ((n0 - 1024) & 63); }
  int bh = b*16 + h;
  size_t ob = ((size_t)bh * 1024 + s) * 128 + d2_0;
  float l0 = Lpart[(size_t)bh * 1024 + s];
  float l1 = Lpart[32768 + (size_t)bh * 1024 + s];
  float l2 = Lpart[65536 + (size_t)bh * 1024 + s];
  float inv = 1.f / (l0 + l1 + l2);
  float4 x0 = *(const float4*)&Opart[ob];
  float4 x1 = *(const float4*)&Opart[ob + 4];
  float4 y0 = *(const float4*)&Opart[ob + TS];
  float4 y1 = *(const float4*)&Opart[ob + TS + 4];
  float4 z0 = *(const float4*)&Opart[ob + 2*TS];
  float4 z1 = *(const float4*)&Opart[ob + 2*TS + 4];
  US8 o;
  o.u[0] = f2bf((x0.x + y0.x + z0.x) * inv); o.u[1] = f2bf((x0.y + y0.y + z0.y) * inv);
  o.u[2] = f2bf((x0.z + y0.z + z0.z) * inv); o.u[3] = f2bf((x0.w + y0.w + z0.w) * inv);
  o.u[4] = f2bf((x1.x + y1.x + z1.x) * inv); o.u[5] = f2bf((x1.y + y1.y + z1.y) * inv);
  o.u[6] = f2bf((x1.z + y1.z + z1.z) * inv); o.u[7] = f2bf((x1.w + y1.w + z1.w) * inv);
  *(US8*)&Ao[idx] = o;
}

// ---------- launch ----------
extern "C" void kernel_launch(void* const* d_in, const int* in_sizes, int n_in,
                              void* d_out, int out_size, void* d_ws, size_t ws_size,
                              hipStream_t stream)
{
  (void)in_sizes; (void)n_in; (void)out_size; (void)ws_size;
  const float* hre = (const float*)d_in[0];
  const float* him = (const float*)d_in[1];
  const float* Kcr = (const float*)d_in[2];
  const float* Kci = (const float*)d_in[3];
  const float* Vcr = (const float*)d_in[4];
  const float* Vci = (const float*)d_in[5];
  const float* gamma = (const float*)d_in[6];
  const float* bre = (const float*)d_in[7];
  const float* bim = (const float*)d_in[8];
  const float* qWr = (const float*)d_in[9];
  const float* qWi = (const float*)d_in[10];
  const float* qbr = (const float*)d_in[11];
  const float* qbi = (const float*)d_in[12];
  const float* kWr = (const float*)d_in[13];
  const float* kWi = (const float*)d_in[14];
  const float* kbr = (const float*)d_in[15];
  const float* kbi = (const float*)d_in[16];
  const float* vWr = (const float*)d_in[17];
  const float* vWi = (const float*)d_in[18];
  const float* vbr = (const float*)d_in[19];
  const float* vbi = (const float*)d_in[20];
  const float* oWr = (const float*)d_in[21];
  const float* oWi = (const float*)d_in[22];
  const float* obr = (const float*)d_in[23];
  const float* obi = (const float*)d_in[24];
  float* out = (float*)d_out;

  char* ws = (char*)d_ws;
  size_t off = 0;
  auto carve = [&](size_t bytes) {
    char* p = ws + off;
    off += (bytes + 255) & ~(size_t)255;
    return p;
  };
  unsigned short* Aln  = (unsigned short*)carve(2048ull * 2048 * 2);       // 8 MB (dead after gemm; reused as Ao)
  unsigned short* Wc   = (unsigned short*)carve(4ull * 2048 * 2048 * 2);   // 32 MB
  float*          bc   = (float*)carve(4ull * 2048 * 4);                   // 32 KB
  unsigned short* Qp   = (unsigned short*)carve(4194304ull * 2);           // 8 MB
  unsigned short* Kp   = (unsigned short*)carve(16777216ull * 2);          // 32 MB
  unsigned short* Vt   = (unsigned short*)carve(16777216ull * 2);          // 32 MB
  float*          Opart= (float*)carve(3ull * 32 * 1024 * 128 * 4);        // 48 MB
  float*          Lpart= (float*)carve(3ull * 32 * 1024 * 4);              // 384 KB

  unsigned short* Ao = Aln;   // alias: Aln dead after gemm, combine runs later

  // output chunk offsets (floats)
  float* out_Kre = out + 4194304;
  float* out_Kim = out + 4194304 + 8388608;
  float* out_Vre = out + 4194304 + 2 * 8388608;
  float* out_Vim = out + 4194304 + 3 * 8388608;

  hipLaunchKernelGGL(prep_kernel, dim3(10272), dim3(256), 0, stream,
                     hre, him, gamma, bre, bim, Aln,
                     qWr, qWi, kWr, kWi, vWr, vWi, oWr, oWi, Wc,
                     qbr, qbi, kbr, kbi, vbr, vbi, obr, obi, bc);
  hipLaunchKernelGGL(gemm_qkv_pack_kernel, dim3(13056), dim3(256), 0, stream,
                     Aln, Wc, bc, Qp, Kp, out_Kre, out_Kim, out_Vre, out_Vim,
                     Kcr, Kci);
  hipLaunchKernelGGL(pack_vt_fused_kernel, dim3(2048), dim3(256), 0, stream,
                     Vcr, Vci, out_Vre, out_Vim, Vt);
  hipLaunchKernelGGL(attn_kernel, dim3(32, 8, 3), dim3(256), 0, stream,
                     Qp, Kp, Vt, Opart, Lpart);
  hipLaunchKernelGGL(attn_combine_kernel, dim3(2048), dim3(256), 0, stream,
                     Opart, Lpart, Ao);
  hipLaunchKernelGGL(gemm_oproj_kernel, dim3(16, 16), dim3(256), 0, stream,
                     Ao, Wc + 3ull * 2048 * 2048, bc + 3 * 2048, hre, him, out);
}

// Round 6
// 553.739 us; speedup vs baseline: 1.1023x; 1.0315x over previous
//
#include <hip/hip_runtime.h>
#include <hip/hip_bf16.h>
#include <cstdint>
#include <cstddef>

// ---------- types ----------
typedef __bf16 bf16x8 __attribute__((ext_vector_type(8)));
typedef float  f32x4  __attribute__((ext_vector_type(4)));

__device__ __forceinline__ unsigned short f2bf(float f) {
  union { float f; unsigned u; } v; v.f = f;
  unsigned u = v.u;
  u += 0x7FFFu + ((u >> 16) & 1u);   // RNE
  return (unsigned short)(u >> 16);
}

__device__ __forceinline__ unsigned short f2bf_cvt(float f) {
  __bf16 h = (__bf16)f;
  return __builtin_bit_cast(unsigned short, h);
}

struct alignas(16) US8 { unsigned short u[8]; };

__device__ __forceinline__ void g2lds16(const void* g, void* l) {
  __builtin_amdgcn_global_load_lds(
      (const __attribute__((address_space(1))) unsigned int*)g,
      (__attribute__((address_space(3))) unsigned int*)l, 16, 0, 0);
}

// sizes
#define BB 2
#define SS 1024
#define HID 1024
#define NHH 16
#define HDD 64
#define TT 4096
#define CCH 3072
// Q pre-scale: 1/sqrt(64) * log2(e)  (scores then exponentiated with raw v_exp_f32 = 2^x)
#define QSCALE (0.125f * 1.44269504088896f)

// ---------- merged prep: wprep (blocks 0..8191) + ln (8192..10239) + bprep (10240..10271) ----------
__global__ __launch_bounds__(256) void prep_kernel(
    const float* __restrict__ hre, const float* __restrict__ him,
    const float* __restrict__ gamma, const float* __restrict__ bre,
    const float* __restrict__ bim, unsigned short* __restrict__ Aln,
    const float* __restrict__ qWr, const float* __restrict__ qWi,
    const float* __restrict__ kWr, const float* __restrict__ kWi,
    const float* __restrict__ vWr, const float* __restrict__ vWi,
    const float* __restrict__ oWr, const float* __restrict__ oWi,
    unsigned short* __restrict__ Wc,
    const float* __restrict__ qbr, const float* __restrict__ qbi,
    const float* __restrict__ kbr, const float* __restrict__ kbi,
    const float* __restrict__ vbr, const float* __restrict__ vbi,
    const float* __restrict__ obr, const float* __restrict__ obi,
    float* __restrict__ bc)
{
  const int bid = blockIdx.x;
  const int tid = threadIdx.x;
  if (bid < 8192) {
    // ---- wprep ----
    int gid = bid * 256 + tid;
    int idx = gid * 8;                     // over 4*2048*2048
    int p   = idx >> 22;
    int rem = idx & 0x3FFFFF;
    int n   = rem >> 11;
    int k   = rem & 2047;
    const float* Wr; const float* Wi;
    switch (p) {
      case 0:  Wr = qWr; Wi = qWi; break;
      case 1:  Wr = kWr; Wi = kWi; break;
      case 2:  Wr = vWr; Wi = vWi; break;
      default: Wr = oWr; Wi = oWi; break;
    }
    const float* src; float sgn = 1.f;
    if (n < 1024) {
      if (k < 1024) src = Wr + (size_t)n * 1024 + k;
      else        { src = Wi + (size_t)n * 1024 + (k - 1024); sgn = -1.f; }
    } else {
      if (k < 1024) src = Wi + (size_t)(n - 1024) * 1024 + k;
      else          src = Wr + (size_t)(n - 1024) * 1024 + (k - 1024);
    }
    float4 a = ((const float4*)src)[0];
    float4 b = ((const float4*)src)[1];
    US8 o;
    o.u[0] = f2bf(a.x * sgn); o.u[1] = f2bf(a.y * sgn);
    o.u[2] = f2bf(a.z * sgn); o.u[3] = f2bf(a.w * sgn);
    o.u[4] = f2bf(b.x * sgn); o.u[5] = f2bf(b.y * sgn);
    o.u[6] = f2bf(b.z * sgn); o.u[7] = f2bf(b.w * sgn);
    *(US8*)&Wc[idx] = o;
  } else if (bid < 10240) {
    // ---- layernorm ----
    int m = bid - 8192;
    const float4 vr = ((const float4*)(hre + (size_t)m * HID))[tid];
    const float4 vi = ((const float4*)(him + (size_t)m * HID))[tid];
    float sr = vr.x + vr.y + vr.z + vr.w;
    float si = vi.x + vi.y + vi.z + vi.w;
    float sq = vr.x*vr.x + vr.y*vr.y + vr.z*vr.z + vr.w*vr.w
             + vi.x*vi.x + vi.y*vi.y + vi.z*vi.z + vi.w*vi.w;
    __shared__ float red[3][4];
    int lane = tid & 63, w = tid >> 6;
    for (int off = 32; off; off >>= 1) {
      sr += __shfl_down(sr, off, 64);
      si += __shfl_down(si, off, 64);
      sq += __shfl_down(sq, off, 64);
    }
    if (lane == 0) { red[0][w] = sr; red[1][w] = si; red[2][w] = sq; }
    __syncthreads();
    sr = red[0][0] + red[0][1] + red[0][2] + red[0][3];
    si = red[1][0] + red[1][1] + red[1][2] + red[1][3];
    sq = red[2][0] + red[2][1] + red[2][2] + red[2][3];
    float mur = sr * (1.f/1024.f), mui = si * (1.f/1024.f);
    float var = sq * (1.f/1024.f) - mur*mur - mui*mui;
    float inv = rsqrtf(var + 1e-5f);
    int k = tid * 4;
    float4 g  = ((const float4*)gamma)[tid];
    float4 br = ((const float4*)bre)[tid];
    float4 bi = ((const float4*)bim)[tid];
    ushort4 nr, ni;
    nr.x = f2bf((vr.x - mur) * inv * g.x + br.x);
    nr.y = f2bf((vr.y - mur) * inv * g.y + br.y);
    nr.z = f2bf((vr.z - mur) * inv * g.z + br.z);
    nr.w = f2bf((vr.w - mur) * inv * g.w + br.w);
    ni.x = f2bf((vi.x - mui) * inv * g.x + bi.x);
    ni.y = f2bf((vi.y - mui) * inv * g.y + bi.y);
    ni.z = f2bf((vi.z - mui) * inv * g.z + bi.z);
    ni.w = f2bf((vi.w - mui) * inv * g.w + bi.w);
    *(ushort4*)&Aln[(size_t)m * 2048 + k]        = nr;
    *(ushort4*)&Aln[(size_t)m * 2048 + 1024 + k] = ni;
  } else {
    // ---- bias prep ----
    int idx = (bid - 10240) * 256 + tid;  // 8192
    int p = idx >> 11, n = idx & 2047;
    const float* br; const float* bi;
    switch (p) {
      case 0:  br = qbr; bi = qbi; break;
      case 1:  br = kbr; bi = kbi; break;
      case 2:  br = vbr; bi = vbi; break;
      default: br = obr; bi = obi; break;
    }
    bc[idx] = (n < 1024) ? br[n] : bi[n - 1024];
  }
}

// ---------- QKV GEMM: 128x256 tile, 512 threads (8 waves), 3-buffer counted-vmcnt ----------
// LDS = 3*(8+16) KB = 72 KB -> 2 blocks/CU = 16 waves/CU (was 12 at 128^2).
// 3 loads/thread/K-step (A:1, B:2). Each wave waits its own vmcnt(3), then
// barrier -> collective visibility (proven pattern from r4 gemm).
// Blocks 0..383 = GEMM; 384..6527 = K-cache pack (streaming backfill).
__global__ __launch_bounds__(512) void gemm_qkv_pack_kernel(
    const unsigned short* __restrict__ A, const unsigned short* __restrict__ Bm,
    const float* __restrict__ bias,
    unsigned short* __restrict__ Qp, unsigned short* __restrict__ Kp,
    float* __restrict__ out_Kre, float* __restrict__ out_Kim,
    float* __restrict__ out_Vre, float* __restrict__ out_Vim,
    const float* __restrict__ Kcr, const float* __restrict__ Kci)
{
  __shared__ alignas(16) unsigned short As[3][128][32];   // 24 KB
  __shared__ alignas(16) unsigned short Bs[3][256][32];   // 48 KB
  const int tid = threadIdx.x;
  if (blockIdx.x >= 384) {
    // ---- pack_kcache: cache -> Kp bf16 [bh][t<3072][128] + out_K f32 ----
    int pk = blockIdx.x - 384;
    int bh = pk / 192;
    int xx = pk % 192;
    int idx = (xx * 512 + tid) * 4;   // over 3072*128
    int d2 = idx & 127;
    int t  = idx >> 7;                // 0..3071
    int b = bh >> 4, h = bh & 15;
    int d = d2 & 63;
    bool im = d2 >= 64;
    const float* src = im ? Kci : Kcr;
    float4 v = *(const float4*)&src[(((size_t)b * CCH + t) * 16 + h) * 64 + d];
    ushort4 o;
    o.x = f2bf(v.x); o.y = f2bf(v.y); o.z = f2bf(v.z); o.w = f2bf(v.w);
    *(ushort4*)&Kp[((size_t)bh * 4096 + t) * 128 + d2] = o;
    float* dst = im ? out_Kim : out_Kre;
    *(float4*)&dst[(((size_t)b * 4096 + t) * 16 + h) * 64 + d] = v;
    return;
  }
  // ---- GEMM ----
  const int K = 2048;
  const int NT = K / 32;   // 64
  int bm = (blockIdx.x / 24) * 128;
  int bn = (blockIdx.x % 24) * 256;
  int lane = tid & 63, w = tid >> 6;          // 8 waves
  int wm = (w >> 2) * 64, wn = (w & 3) * 64;  // 2x4 wave grid over 128x256
  int l15 = lane & 15, q = lane >> 4;
  int lr = tid >> 2;                          // staged row 0..127
  int lcs = ((tid & 3) ^ ((tid >> 3) & 3)) * 8;  // source chunk, XOR-swizzled

  const unsigned short* Ag  = A  + (size_t)(bm + lr)       * K + lcs;
  const unsigned short* Bg0 = Bm + (size_t)(bn + lr)       * K + lcs;
  const unsigned short* Bg1 = Bm + (size_t)(bn + lr + 128) * K + lcs;
  const int rsw = ((l15 >> 1) & 3);           // read-side XOR == (row>>1)&3

  f32x4 acc[4][4] = {};

  auto stage = [&](int b, int t) {
    int k0 = t * 32;
    g2lds16(Ag  + k0, (unsigned short*)As[b] + 8*tid);
    g2lds16(Bg0 + k0, (unsigned short*)Bs[b] + 8*tid);
    g2lds16(Bg1 + k0, (unsigned short*)Bs[b] + 4096 + 8*tid);
  };

  stage(0, 0);
  stage(1, 1);

  int bc_ = 0, bp_ = 2;
  for (int t = 0; t < NT; ++t) {
    if (t + 1 < NT) asm volatile("s_waitcnt vmcnt(3)" ::: "memory");
    else            asm volatile("s_waitcnt vmcnt(0)" ::: "memory");
    __builtin_amdgcn_s_barrier();
    __builtin_amdgcn_sched_barrier(0);
    if (t + 2 < NT) stage(bp_, t + 2);

    bf16x8 af[4], bfr[4];
#pragma unroll
    for (int i = 0; i < 4; i++) af[i]  = *(const bf16x8*)&As[bc_][wm + i*16 + l15][(q ^ rsw) * 8];
#pragma unroll
    for (int i = 0; i < 4; i++) bfr[i] = *(const bf16x8*)&Bs[bc_][wn + i*16 + l15][(q ^ rsw) * 8];
#pragma unroll
    for (int i = 0; i < 4; i++)
#pragma unroll
      for (int j = 0; j < 4; j++)
        acc[i][j] = __builtin_amdgcn_mfma_f32_16x16x32_bf16(af[i], bfr[j], acc[i][j], 0, 0, 0);

    bc_ = (bc_ == 2) ? 0 : bc_ + 1;
    bp_ = (bp_ == 2) ? 0 : bp_ + 1;
  }

  const int sec = bn >> 11;   // 0=Q, 1=K, 2=V (uniform per block; 2048 % 256 == 0)
#pragma unroll
  for (int i = 0; i < 4; i++)
#pragma unroll
    for (int j = 0; j < 4; j++) {
      int n = bn + wn + j*16 + l15;
      float bv = bias[n];
      int col = n & 2047;
      int re = (col < 1024) ? 1 : 0;
      int h = (col & 1023) >> 6, d = col & 63;
      int d2 = re ? d : 64 + d;
#pragma unroll
      for (int r = 0; r < 4; r++) {
        int m = bm + wm + i*16 + q*4 + r;
        float val = acc[i][j][r] + bv;
        int b = m >> 10, s = m & 1023;
        int bh = b*16 + h;
        if (sec == 0) {
          Qp[((size_t)bh*1024 + s)*128 + d2] = f2bf_cvt(val * QSCALE);
        } else if (sec == 1) {
          int t = CCH + s;
          Kp[((size_t)bh*4096 + t)*128 + d2] = f2bf_cvt(val);
          float* dst = re ? out_Kre : out_Kim;
          dst[(((size_t)b*4096 + t)*16 + h)*64 + d] = val;
        } else {
          int t = CCH + s;
          float* dst = re ? out_Vre : out_Vim;
          dst[(((size_t)b*4096 + t)*16 + h)*64 + d] = val;
        }
      }
    }
}

// ---------- o-proj GEMM with residual + split write (pipelined, 128^2) ----------
__global__ __launch_bounds__(256) void gemm_oproj_kernel(
    const unsigned short* __restrict__ A, const unsigned short* __restrict__ Bm,
    const float* __restrict__ bias, const float* __restrict__ hre,
    const float* __restrict__ him, float* __restrict__ out)
{
  __shared__ alignas(16) unsigned short As[3][128][32];
  __shared__ alignas(16) unsigned short Bs[3][128][32];
  const int K = 2048;
  const int NT = K / 32;
  int bm = blockIdx.y * 128;
  int bn = blockIdx.x * 128;
  int tid = threadIdx.x;
  int lane = tid & 63, w = tid >> 6;
  int wm = (w >> 1) * 64, wn = (w & 1) * 64;
  int l15 = lane & 15, q = lane >> 4;
  int lr = tid >> 2;
  int lcs = ((tid & 3) ^ ((tid >> 3) & 3)) * 8;

  const unsigned short* A0 = A  + (size_t)(bm + lr)      * K + lcs;
  const unsigned short* A1 = A  + (size_t)(bm + lr + 64) * K + lcs;
  const unsigned short* B0 = Bm + (size_t)(bn + lr)      * K + lcs;
  const unsigned short* B1 = Bm + (size_t)(bn + lr + 64) * K + lcs;
  const int rsw = ((l15 >> 1) & 3);

  f32x4 acc[4][4] = {};

  auto stage = [&](int b, int t) {
    int k0 = t * 32;
    g2lds16(A0 + k0, (unsigned short*)As[b] + 8*tid);
    g2lds16(A1 + k0, (unsigned short*)As[b] + 2048 + 8*tid);
    g2lds16(B0 + k0, (unsigned short*)Bs[b] + 8*tid);
    g2lds16(B1 + k0, (unsigned short*)Bs[b] + 2048 + 8*tid);
  };

  stage(0, 0);
  stage(1, 1);

  int bc_ = 0, bp_ = 2;
  for (int t = 0; t < NT; ++t) {
    if (t + 1 < NT) asm volatile("s_waitcnt vmcnt(4)" ::: "memory");
    else            asm volatile("s_waitcnt vmcnt(0)" ::: "memory");
    __builtin_amdgcn_s_barrier();
    __builtin_amdgcn_sched_barrier(0);
    if (t + 2 < NT) stage(bp_, t + 2);

    bf16x8 af[4], bfr[4];
#pragma unroll
    for (int i = 0; i < 4; i++) af[i]  = *(const bf16x8*)&As[bc_][wm + i*16 + l15][(q ^ rsw) * 8];
#pragma unroll
    for (int i = 0; i < 4; i++) bfr[i] = *(const bf16x8*)&Bs[bc_][wn + i*16 + l15][(q ^ rsw) * 8];
#pragma unroll
    for (int i = 0; i < 4; i++)
#pragma unroll
      for (int j = 0; j < 4; j++)
        acc[i][j] = __builtin_amdgcn_mfma_f32_16x16x32_bf16(af[i], bfr[j], acc[i][j], 0, 0, 0);

    bc_ = (bc_ == 2) ? 0 : bc_ + 1;
    bp_ = (bp_ == 2) ? 0 : bp_ + 1;
  }

#pragma unroll
  for (int i = 0; i < 4; i++)
#pragma unroll
    for (int j = 0; j < 4; j++) {
      int n = bn + wn + j*16 + l15;
      float bv = bias[n];
#pragma unroll
      for (int r = 0; r < 4; r++) {
        int m = bm + wm + i*16 + q*4 + r;
        float val = acc[i][j][r] + bv;
        if (n < 1024) out[(size_t)m * 1024 + n] = val + hre[(size_t)m * 1024 + n];
        else out[2097152 + (size_t)m * 1024 + (n - 1024)] = val + him[(size_t)m * 1024 + (n - 1024)];
      }
    }
}

// ---------- fused V: cache -> out_V f32 (+readback of new part) -> Vt bf16 [bh][d2][t] ----------
__global__ __launch_bounds__(256) void pack_vt_fused_kernel(
    const float* __restrict__ Vc_re, const float* __restrict__ Vc_im,
    float* __restrict__ out_Vre, float* __restrict__ out_Vim,
    unsigned short* __restrict__ Vt)
{
  __shared__ float Ts[64][136];
  const int ty = blockIdx.x & 63;   // t-tile
  const int bh = blockIdx.x >> 6;   // 0..31
  const int b = bh >> 4, h = bh & 15;
  const int t0 = ty * 64;
  const int tid = threadIdx.x;
#pragma unroll
  for (int rr = 0; rr < 8; rr++) {
    int j = rr * 256 + tid;
    int t_loc = j >> 5, c = j & 31;
    int d2 = c * 4;
    int t = t0 + t_loc;
    int d = (d2 < 64) ? d2 : d2 - 64;
    float4 v;
    if (t < CCH) {
      const float* src = (d2 < 64) ? Vc_re : Vc_im;
      v = *(const float4*)&src[(((size_t)b * CCH + t) * 16 + h) * 64 + d];
      float* dst = (d2 < 64) ? out_Vre : out_Vim;
      *(float4*)&dst[(((size_t)b * 4096 + t) * 16 + h) * 64 + d] = v;
    } else {
      const float* src = (d2 < 64) ? out_Vre : out_Vim;   // written by gemm_qkv
      v = *(const float4*)&src[(((size_t)b * 4096 + t) * 16 + h) * 64 + d];
    }
    *(float4*)&Ts[t_loc][d2] = v;
  }
  __syncthreads();
  const int d2 = tid >> 1, half = tid & 1;
  unsigned short tmp[32];
#pragma unroll
  for (int i = 0; i < 32; i++) tmp[i] = f2bf(Ts[half*32 + i][d2]);
  size_t dst = (size_t)bh * 128 * 4096 + (size_t)d2 * 4096 + t0 + half*32;
#pragma unroll
  for (int kq = 0; kq < 4; kq++)
    *(US8*)&Vt[dst + kq*8] = *(US8*)&tmp[kq*8];
}

// ---------- flash attention (r4 version): 128 q-rows/block, T=32 tiles, 3-way t-split ----------
// LDS = Ks 16K + Vs 16K + Ps 10K = 42 KB -> 3 blocks/CU (12 waves/CU).
__global__ __launch_bounds__(256) void attn_kernel(
    const unsigned short* __restrict__ Qp, const unsigned short* __restrict__ Kp,
    const unsigned short* __restrict__ Vt, float* __restrict__ Opart,
    float* __restrict__ Lpart)
{
  const int bh   = blockIdx.x;   // 0..31
  const int sblk = blockIdx.y;   // 0..7
  const int tpar = blockIdx.z;   // 0..2
  const int s0 = sblk * 128;
  const int tid = threadIdx.x;
  const int lane = tid & 63, w = tid >> 6;
  const int l15 = lane & 15, q = lane >> 4;

  __shared__ alignas(16) unsigned short Ks[2][32][128];  // 16 KB
  __shared__ alignas(16) unsigned short Vs[2][128][32];  // 16 KB
  __shared__ alignas(16) unsigned short Ps[4][32][40];   // 10 KB (padded rows)

  // persistent Q fragments
  bf16x8 qf[2][4];
#pragma unroll
  for (int mi = 0; mi < 2; mi++) {
    const size_t qb = ((size_t)bh * 1024 + s0 + w*32 + mi*16 + l15) * 128;
#pragma unroll
    for (int kc = 0; kc < 4; kc++)
      qf[mi][kc] = *(const bf16x8*)&Qp[qb + kc*32 + q*8];
  }

  f32x4 oacc[2][8] = {};
  float lsum[2][4] = {};

  const size_t kpb = (size_t)bh * 4096 * 128;
  const size_t vtb = (size_t)bh * 128 * 4096;
  const int n_tiles = 4*sblk + 100;   // tiles of 32 t
  const int n_safe  = n_tiles - 4;

  auto issue = [&](int buf, int t0) {
#pragma unroll
    for (int kk = 0; kk < 2; kk++) {
      int j = (w*2 + kk)*64 + lane;          // chunk 0..511
      int r = j >> 4, p = j & 15, c = p ^ (r & 7);
      g2lds16(&Kp[kpb + (size_t)(t0 + r) * 128 + c*8],
              (unsigned short*)&Ks[buf][0][0] + (size_t)j * 8);
    }
#pragma unroll
    for (int kk = 0; kk < 2; kk++) {
      int j = (w*2 + kk)*64 + lane;
      int r = j >> 2, p = j & 3, c = p ^ ((r >> 1) & 3);
      g2lds16(&Vt[vtb + (size_t)r * 4096 + t0 + c*8],
              (unsigned short*)&Vs[buf][0][0] + (size_t)j * 8);
    }
  };

  int buf = 0;
  issue(0, tpar * 32);

  for (int it = tpar; it < n_tiles; it += 3) {
    __syncthreads();                       // drains loads for `buf`
    if (it + 3 < n_tiles) issue(buf ^ 1, (it + 3) * 32);   // overlap with compute

    // QK^T  (32 t-cols per tile: nc = 0,1)
    f32x4 sacc[2][2] = {};
    __builtin_amdgcn_s_setprio(1);
#pragma unroll
    for (int kc = 0; kc < 4; kc++) {
      bf16x8 kf[2];
#pragma unroll
      for (int nc = 0; nc < 2; nc++)
        kf[nc] = *(const bf16x8*)&Ks[buf][nc*16 + l15][((kc*4 + q) ^ (l15 & 7)) * 8];
#pragma unroll
      for (int mi = 0; mi < 2; mi++)
#pragma unroll
        for (int nc = 0; nc < 2; nc++)
          sacc[mi][nc] = __builtin_amdgcn_mfma_f32_16x16x32_bf16(qf[mi][kc], kf[nc], sacc[mi][nc], 0, 0, 0);
    }
    __builtin_amdgcn_s_setprio(0);

    // exp2 + P store, mask only last 4 tiles
    const bool safe = (it < n_safe);
    const int t0 = it << 5;
#pragma unroll
    for (int mi = 0; mi < 2; mi++)
#pragma unroll
      for (int r = 0; r < 4; r++) {
        const int rr = mi*16 + q*4 + r;
        const int rel = s0 + w*32 + rr + CCH - t0;
        float ls = 0.f;
#pragma unroll
        for (int nc = 0; nc < 2; nc++) {
          float p;
          asm("v_exp_f32 %0, %1" : "=v"(p) : "v"(sacc[mi][nc][r]));   // 2^x
          if (!safe && (nc*16 + l15 > rel)) p = 0.f;
          ls += p;
          Ps[w][rr][nc*16 + l15] = f2bf_cvt(p);
        }
        lsum[mi][r] += ls;
      }

    // PV (single 32-k chunk)
    bf16x8 pf[2];
#pragma unroll
    for (int mi = 0; mi < 2; mi++)
      pf[mi] = *(const bf16x8*)&Ps[w][mi*16 + l15][q*8];
    __builtin_amdgcn_s_setprio(1);
#pragma unroll
    for (int dc = 0; dc < 8; dc++) {
      int d2 = dc*16 + l15;
      bf16x8 vfr = *(const bf16x8*)&Vs[buf][d2][(q ^ ((d2 >> 1) & 3)) * 8];
#pragma unroll
      for (int mi = 0; mi < 2; mi++)
        oacc[mi][dc] = __builtin_amdgcn_mfma_f32_16x16x32_bf16(pf[mi], vfr, oacc[mi][dc], 0, 0, 0);
    }
    __builtin_amdgcn_s_setprio(0);
    buf ^= 1;
  }

  // write partials
  const size_t pb = ((size_t)tpar * 32 + bh) * 1024 + s0 + w*32;
#pragma unroll
  for (int mi = 0; mi < 2; mi++)
#pragma unroll
    for (int r = 0; r < 4; r++) {
      float l = lsum[mi][r];
      l += __shfl_xor(l, 1, 64);
      l += __shfl_xor(l, 2, 64);
      l += __shfl_xor(l, 4, 64);
      l += __shfl_xor(l, 8, 64);
      if (l15 == 0) Lpart[pb + mi*16 + q*4 + r] = l;
    }
#pragma unroll
  for (int mi = 0; mi < 2; mi++)
#pragma unroll
    for (int dc = 0; dc < 8; dc++)
#pragma unroll
      for (int r = 0; r < 4; r++)
        Opart[(pb + mi*16 + q*4 + r) * 128 + dc*16 + l15] = oacc[mi][dc][r];
}

// ---------- combine 3 partials -> Ao bf16 [m][2048] ----------
__global__ __launch_bounds__(256) void attn_combine_kernel(
    const float* __restrict__ Opart, const float* __restrict__ Lpart,
    unsigned short* __restrict__ Ao)
{
  const size_t TS = 4194304ull;   // tpar stride in floats (32*1024*128)
  int gid = blockIdx.x * 256 + threadIdx.x;
  int idx = gid * 8;              // over 2048*2048
  int m = idx >> 11, n0 = idx & 2047;
  int b = m >> 10, s = m & 1023;
  int h, d2_0;
  if (n0 < 1024) { h = n0 >> 6; d2_0 = n0 & 63; }
  else { h = (n0 - 1024) >> 6; d2_0 = 64 + ((n0 - 1024) & 63); }
  int bh = b*16 + h;
  size_t ob = ((size_t)bh * 1024 + s) * 128 + d2_0;
  float l0 = Lpart[(size_t)bh * 1024 + s];
  float l1 = Lpart[32768 + (size_t)bh * 1024 + s];
  float l2 = Lpart[65536 + (size_t)bh * 1024 + s];
  float inv = 1.f / (l0 + l1 + l2);
  float4 x0 = *(const float4*)&Opart[ob];
  float4 x1 = *(const float4*)&Opart[ob + 4];
  float4 y0 = *(const float4*)&Opart[ob + TS];
  float4 y1 = *(const float4*)&Opart[ob + TS + 4];
  float4 z0 = *(const float4*)&Opart[ob + 2*TS];
  float4 z1 = *(const float4*)&Opart[ob + 2*TS + 4];
  US8 o;
  o.u[0] = f2bf((x0.x + y0.x + z0.x) * inv); o.u[1] = f2bf((x0.y + y0.y + z0.y) * inv);
  o.u[2] = f2bf((x0.z + y0.z + z0.z) * inv); o.u[3] = f2bf((x0.w + y0.w + z0.w) * inv);
  o.u[4] = f2bf((x1.x + y1.x + z1.x) * inv); o.u[5] = f2bf((x1.y + y1.y + z1.y) * inv);
  o.u[6] = f2bf((x1.z + y1.z + z1.z) * inv); o.u[7] = f2bf((x1.w + y1.w + z1.w) * inv);
  *(US8*)&Ao[idx] = o;
}

// ---------- launch ----------
extern "C" void kernel_launch(void* const* d_in, const int* in_sizes, int n_in,
                              void* d_out, int out_size, void* d_ws, size_t ws_size,
                              hipStream_t stream)
{
  (void)in_sizes; (void)n_in; (void)out_size; (void)ws_size;
  const float* hre = (const float*)d_in[0];
  const float* him = (const float*)d_in[1];
  const float* Kcr = (const float*)d_in[2];
  const float* Kci = (const float*)d_in[3];
  const float* Vcr = (const float*)d_in[4];
  const float* Vci = (const float*)d_in[5];
  const float* gamma = (const float*)d_in[6];
  const float* bre = (const float*)d_in[7];
  const float* bim = (const float*)d_in[8];
  const float* qWr = (const float*)d_in[9];
  const float* qWi = (const float*)d_in[10];
  const float* qbr = (const float*)d_in[11];
  const float* qbi = (const float*)d_in[12];
  const float* kWr = (const float*)d_in[13];
  const float* kWi = (const float*)d_in[14];
  const float* kbr = (const float*)d_in[15];
  const float* kbi = (const float*)d_in[16];
  const float* vWr = (const float*)d_in[17];
  const float* vWi = (const float*)d_in[18];
  const float* vbr = (const float*)d_in[19];
  const float* vbi = (const float*)d_in[20];
  const float* oWr = (const float*)d_in[21];
  const float* oWi = (const float*)d_in[22];
  const float* obr = (const float*)d_in[23];
  const float* obi = (const float*)d_in[24];
  float* out = (float*)d_out;

  char* ws = (char*)d_ws;
  size_t off = 0;
  auto carve = [&](size_t bytes) {
    char* p = ws + off;
    off += (bytes + 255) & ~(size_t)255;
    return p;
  };
  unsigned short* Aln  = (unsigned short*)carve(2048ull * 2048 * 2);       // 8 MB (dead after gemm; reused as Ao)
  unsigned short* Wc   = (unsigned short*)carve(4ull * 2048 * 2048 * 2);   // 32 MB
  float*          bc   = (float*)carve(4ull * 2048 * 4);                   // 32 KB
  unsigned short* Qp   = (unsigned short*)carve(4194304ull * 2);           // 8 MB
  unsigned short* Kp   = (unsigned short*)carve(16777216ull * 2);          // 32 MB
  unsigned short* Vt   = (unsigned short*)carve(16777216ull * 2);          // 32 MB
  float*          Opart= (float*)carve(3ull * 32 * 1024 * 128 * 4);        // 48 MB
  float*          Lpart= (float*)carve(3ull * 32 * 1024 * 4);              // 384 KB

  unsigned short* Ao = Aln;   // alias: Aln dead after gemm, combine runs later

  // output chunk offsets (floats)
  float* out_Kre = out + 4194304;
  float* out_Kim = out + 4194304 + 8388608;
  float* out_Vre = out + 4194304 + 2 * 8388608;
  float* out_Vim = out + 4194304 + 3 * 8388608;

  hipLaunchKernelGGL(prep_kernel, dim3(10272), dim3(256), 0, stream,
                     hre, him, gamma, bre, bim, Aln,
                     qWr, qWi, kWr, kWi, vWr, vWi, oWr, oWi, Wc,
                     qbr, qbi, kbr, kbi, vbr, vbi, obr, obi, bc);
  hipLaunchKernelGGL(gemm_qkv_pack_kernel, dim3(6528), dim3(512), 0, stream,
                     Aln, Wc, bc, Qp, Kp, out_Kre, out_Kim, out_Vre, out_Vim,
                     Kcr, Kci);
  hipLaunchKernelGGL(pack_vt_fused_kernel, dim3(2048), dim3(256), 0, stream,
                     Vcr, Vci, out_Vre, out_Vim, Vt);
  hipLaunchKernelGGL(attn_kernel, dim3(32, 8, 3), dim3(256), 0, stream,
                     Qp, Kp, Vt, Opart, Lpart);
  hipLaunchKernelGGL(attn_combine_kernel, dim3(2048), dim3(256), 0, stream,
                     Opart, Lpart, Ao);
  hipLaunchKernelGGL(gemm_oproj_kernel, dim3(16, 16), dim3(256), 0, stream,
                     Ao, Wc + 3ull * 2048 * 2048, bc + 3 * 2048, hre, him, out);
}